// Round 13
// baseline (371.223 us; speedup 1.0000x reference)
//
#include <hip/hip_runtime.h>
#include <stdint.h>
#include <stddef.h>

#define LSEQ   2048
#define DMODEL 2048
#define NH     32
#define DINNER 2048
#define PROJ   8224
#define PROJP  8192   // bf16 GEMM width: x,z,b,c only (a_log handled in fp32)
#define NC     16     // scan chunks
#define CHUNK  128    // LSEQ / NC

typedef __attribute__((ext_vector_type(4))) float f32x4;
typedef __attribute__((ext_vector_type(8))) __bf16 bf16x8;
typedef __attribute__((ext_vector_type(8))) unsigned short u16x8;

__device__ __forceinline__ unsigned short f2bf(float f) {
  union { float f; unsigned u; } uu; uu.f = f;
  unsigned r = uu.u + 0x7FFFu + ((uu.u >> 16) & 1u);
  return (unsigned short)(r >> 16);
}
__device__ __forceinline__ float bf2f(unsigned short u) {
  union { unsigned u; float f; } x; x.u = ((unsigned)u) << 16; return x.f;
}

__device__ __forceinline__ void gl_lds16(const void* g, void* l) {
  __builtin_amdgcn_global_load_lds(
      (__attribute__((address_space(1))) const void*)g,
      (__attribute__((address_space(3))) void*)l, 16, 0, 0);
}

// ---------------- conversions ----------------
__global__ __launch_bounds__(256) void cvt_f32_bf16(
    const float* __restrict__ in, unsigned short* __restrict__ out, int n) {
  int i = (blockIdx.x * 256 + threadIdx.x) * 4;
  if (i + 3 < n) {
    f32x4 v = *(const f32x4*)(in + i);
    ushort4 o;
    o.x = f2bf(v[0]); o.y = f2bf(v[1]); o.z = f2bf(v[2]); o.w = f2bf(v[3]);
    *(ushort4*)(out + i) = o;
  }
}

// ---------------- 256x256 bf16 NT GEMM, BK=64, counted-vmcnt quadrant phases ----
// Wave wid owns rows {iw*32..+32}U{128+iw*32..+32}, cols {jw*64..+64}U{128+jw*64}
// (iw=wid&3, jw=wid>>2) -> every wave needs the SAME (A-half,B-half) per phase.
// Phases = C-quadrants: P0(A0,B0) P1(A0,B1) P2(A1,B0) P3(A1,B1), 16 MFMA each.
// Stage order for kt+1 (one half = 2 gl_lds/thread per phase): A0,B0,B1,A1.
// Steady-state waits: vmcnt(4) at P0/P1/P2, none at P3 — never drained to 0.
// Last tile: {4,2,0,-}. One barrier per phase (all-waves vmcnt + barrier =
// global certification). Swizzle/fragment/C-map = r7/r10-verified primitives.
__global__ __launch_bounds__(512, 2) void gemm256(
    const unsigned short* __restrict__ A,
    const unsigned short* __restrict__ W,
    unsigned short* __restrict__ C, const int K, const int ldc, const int ntx) {
  __shared__ uint8_t sA[2][32768];
  __shared__ uint8_t sB[2][32768];
  const int tid  = threadIdx.x;
  const int lane = tid & 63;
  const int wid  = tid >> 6;
  const int iw   = wid & 3;        // row group
  const int jw   = wid >> 2;       // col group
  const int nwg = gridDim.x;
  const int wg0 = blockIdx.x;
  const int g   = (wg0 & 7) * (nwg >> 3) + (wg0 >> 3);
  const int grp = ntx * 4;
  const int sr  = g / grp, rem = g % grp;
  const int m0  = (sr * 4 + (rem & 3)) * 256;
  const int n0  = (rem >> 2) * 256;

  // staging addressing (r7-verified): dest byte j*8192 + wid*1024 + lane*16
  // -> row = j*64 + wid*8 + (lane>>3), slot = lane&7; src col-slot = slot^(row&7)
  const int row0 = wid * 8 + (lane >> 3);
  const int ssrc = (lane & 7) ^ (row0 & 7);
  const unsigned short* a_base = A + (size_t)(m0 + row0) * K + ssrc * 8;
  const unsigned short* b_base = W + (size_t)(n0 + row0) * K + ssrc * 8;
  const int wb = wid * 1024;

  f32x4 acc[2][2][2][4] = {};    // [mh][mi][nh][ni]
  const int nk = K >> 6;
  const int rl = lane & 15;
  const int hq = lane >> 4;

  // prologue: stage tile 0 fully (order A0,B0,B1,A1), drain, barrier
  gl_lds16(a_base, &sA[0][wb]);
  gl_lds16(a_base + (size_t)64 * K, &sA[0][8192 + wb]);
  gl_lds16(b_base, &sB[0][wb]);
  gl_lds16(b_base + (size_t)64 * K, &sB[0][8192 + wb]);
  gl_lds16(b_base + (size_t)128 * K, &sB[0][2 * 8192 + wb]);
  gl_lds16(b_base + (size_t)192 * K, &sB[0][3 * 8192 + wb]);
  gl_lds16(a_base + (size_t)128 * K, &sA[0][2 * 8192 + wb]);
  gl_lds16(a_base + (size_t)192 * K, &sA[0][3 * 8192 + wb]);
  asm volatile("s_waitcnt vmcnt(0)" ::: "memory");
  asm volatile("s_barrier" ::: "memory");

#define PHASE(MH, NH)                                                         \
  {                                                                           \
    bf16x8 af[2][2], bv[2][4];                                                \
    _Pragma("unroll")                                                         \
    for (int ks = 0; ks < 2; ++ks) {                                          \
      const int s = ks * 4 + hq;                                              \
      _Pragma("unroll")                                                       \
      for (int mi = 0; mi < 2; ++mi) {                                        \
        const int r = (MH)*128 + iw * 32 + mi * 16 + rl;                      \
        af[ks][mi] = *(const bf16x8*)(&sA[cur][r * 128 + ((s ^ (r & 7)) << 4)]); \
      }                                                                       \
      _Pragma("unroll")                                                       \
      for (int ni = 0; ni < 4; ++ni) {                                        \
        const int r = (NH)*128 + jw * 64 + ni * 16 + rl;                      \
        bv[ks][ni] = *(const bf16x8*)(&sB[cur][r * 128 + ((s ^ (r & 7)) << 4)]); \
      }                                                                       \
    }                                                                         \
    asm volatile("s_waitcnt lgkmcnt(0)" ::: "memory");                        \
    __builtin_amdgcn_s_setprio(1);                                            \
    _Pragma("unroll")                                                         \
    for (int ks = 0; ks < 2; ++ks)                                            \
      _Pragma("unroll")                                                       \
      for (int mi = 0; mi < 2; ++mi)                                          \
        _Pragma("unroll")                                                     \
        for (int ni = 0; ni < 4; ++ni)                                        \
          acc[MH][mi][NH][ni] = __builtin_amdgcn_mfma_f32_16x16x32_bf16(      \
              af[ks][mi], bv[ks][ni], acc[MH][mi][NH][ni], 0, 0, 0);          \
    __builtin_amdgcn_s_setprio(0);                                            \
  }

  for (int kt = 0; kt < nk; ++kt) {
    const int cur = kt & 1;
    const int nb = cur ^ 1;
    const unsigned short* an = a_base + (size_t)(kt + 1) * 64;
    const unsigned short* bn = b_base + (size_t)(kt + 1) * 64;
    const bool more = (kt + 1 < nk);

    // ---- P0: quadrant (A0,B0); stage A0(kt+1) ----
    asm volatile("s_waitcnt vmcnt(4)" ::: "memory");
    asm volatile("s_barrier" ::: "memory");
    if (more) {
      gl_lds16(an, &sA[nb][wb]);
      gl_lds16(an + (size_t)64 * K, &sA[nb][8192 + wb]);
    }
    PHASE(0, 0)

    // ---- P1: quadrant (A0,B1); stage B0(kt+1) ----
    if (more) { asm volatile("s_waitcnt vmcnt(4)" ::: "memory"); }
    else      { asm volatile("s_waitcnt vmcnt(2)" ::: "memory"); }
    asm volatile("s_barrier" ::: "memory");
    if (more) {
      gl_lds16(bn, &sB[nb][wb]);
      gl_lds16(bn + (size_t)64 * K, &sB[nb][8192 + wb]);
    }
    PHASE(0, 1)

    // ---- P2: quadrant (A1,B0); stage B1(kt+1) ----
    if (more) { asm volatile("s_waitcnt vmcnt(4)" ::: "memory"); }
    else      { asm volatile("s_waitcnt vmcnt(0)" ::: "memory"); }
    asm volatile("s_barrier" ::: "memory");
    if (more) {
      gl_lds16(bn + (size_t)128 * K, &sB[nb][2 * 8192 + wb]);
      gl_lds16(bn + (size_t)192 * K, &sB[nb][3 * 8192 + wb]);
    }
    PHASE(1, 0)

    // ---- P3: quadrant (A1,B1) (certified at P1/P2); stage A1(kt+1) ----
    asm volatile("s_barrier" ::: "memory");
    if (more) {
      gl_lds16(an + (size_t)128 * K, &sA[nb][2 * 8192 + wb]);
      gl_lds16(an + (size_t)192 * K, &sA[nb][3 * 8192 + wb]);
    }
    PHASE(1, 1)
  }
#undef PHASE

  // epilogue: D mapping col=lane&15, row=(lane>>4)*4+reg (m89-verified)
#pragma unroll
  for (int mh = 0; mh < 2; ++mh)
#pragma unroll
    for (int mi = 0; mi < 2; ++mi)
#pragma unroll
      for (int nh = 0; nh < 2; ++nh)
#pragma unroll
        for (int ni = 0; ni < 4; ++ni) {
          const int crow = m0 + mh * 128 + iw * 32 + mi * 16 + (lane >> 4) * 4;
          const int ccol = n0 + nh * 128 + jw * 64 + ni * 16 + rl;
          unsigned short* cp = C + (size_t)crow * ldc + ccol;
          cp[0] = f2bf(acc[mh][mi][nh][ni][0]);
          cp[(size_t)ldc] = f2bf(acc[mh][mi][nh][ni][1]);
          cp[2 * (size_t)ldc] = f2bf(acc[mh][mi][nh][ni][2]);
          cp[3 * (size_t)ldc] = f2bf(acc[mh][mi][nh][ni][3]);
        }
}

// ---------------- 128x128 bf16 NT GEMM (gemm2), single-barrier loop ----------------
__global__ __launch_bounds__(256) void gemm_bt(
    const unsigned short* __restrict__ A,
    const unsigned short* __restrict__ W,
    float* __restrict__ C, const int K, const int ldc, const int ntx) {
  __shared__ uint8_t sA[2][128 * 64 * 2];
  __shared__ uint8_t sB[2][128 * 64 * 2];
  const int tid  = threadIdx.x;
  const int lane = tid & 63;
  const int wid  = tid >> 6;
  const int wm   = wid >> 1;
  const int wnn  = wid & 1;
  const int nwg = gridDim.x;
  const int wg0 = blockIdx.x;
  const int g   = (wg0 & 7) * (nwg >> 3) + (wg0 >> 3);
  const int grp = ntx * 4;
  const int sr  = g / grp, rem = g % grp;
  const int m0  = (sr * 4 + (rem & 3)) * 128;
  const int n0  = (rem >> 2) * 128;

  const int rowA = tid >> 3;
  const int slot = (tid & 7) ^ (rowA & 7);
  const unsigned short* a_base = A + (size_t)(m0 + rowA) * K + slot * 8;
  const unsigned short* b_base = W + (size_t)(n0 + rowA) * K + slot * 8;
  const int loff = wid * 1024;

  f32x4 acc[4][4] = {};
  const int nk = K >> 6;

#pragma unroll
  for (int j = 0; j < 4; ++j) {
    gl_lds16(a_base + (size_t)j * 32 * K, &sA[0][loff + j * 4096]);
    gl_lds16(b_base + (size_t)j * 32 * K, &sB[0][loff + j * 4096]);
  }

  for (int kt = 0; kt < nk; ++kt) {
    const int cur = kt & 1;
    asm volatile("s_waitcnt vmcnt(0)" ::: "memory");
    asm volatile("s_barrier" ::: "memory");
    if (kt + 1 < nk) {
      const unsigned short* ak = a_base + (kt + 1) * 64;
      const unsigned short* bk = b_base + (kt + 1) * 64;
      const int nb = cur ^ 1;
#pragma unroll
      for (int j = 0; j < 4; ++j) {
        gl_lds16(ak + (size_t)j * 32 * K, &sA[nb][loff + j * 4096]);
        gl_lds16(bk + (size_t)j * 32 * K, &sB[nb][loff + j * 4096]);
      }
    }

    const int ra = wm * 64 + (lane & 15);
    const int rb = wnn * 64 + (lane & 15);
    const int hq = lane >> 4;
#pragma unroll
    for (int ks = 0; ks < 2; ++ks) {
      bf16x8 af[4], bv[4];
      const int s = ks * 4 + hq;
#pragma unroll
      for (int mi = 0; mi < 4; ++mi) {
        const int r = ra + mi * 16;
        af[mi] = *(const bf16x8*)(&sA[cur][r * 128 + ((s ^ (r & 7)) << 4)]);
      }
#pragma unroll
      for (int ni = 0; ni < 4; ++ni) {
        const int r = rb + ni * 16;
        bv[ni] = *(const bf16x8*)(&sB[cur][r * 128 + ((s ^ (r & 7)) << 4)]);
      }
#pragma unroll
      for (int mi = 0; mi < 4; ++mi)
#pragma unroll
        for (int ni = 0; ni < 4; ++ni)
          acc[mi][ni] = __builtin_amdgcn_mfma_f32_16x16x32_bf16(
              af[mi], bv[ni], acc[mi][ni], 0, 0, 0);
    }
  }

  const int crow = m0 + wm * 64 + (lane >> 4) * 4;
  const int ccol = n0 + wnn * 64 + (lane & 15);
#pragma unroll
  for (int mi = 0; mi < 4; ++mi)
#pragma unroll
    for (int ni = 0; ni < 4; ++ni) {
      float* cp = C + (size_t)(crow + mi * 16) * ldc + ccol + ni * 16;
      cp[0] = acc[mi][ni][0];
      cp[(size_t)ldc] = acc[mi][ni][1];
      cp[2 * (size_t)ldc] = acc[mi][ni][2];
      cp[3 * (size_t)ldc] = acc[mi][ni][3];
    }
}

// ---------------- exact fp32 a_log slab: Alog[4096,32] = x * W_a^T ----------------
#define AR  64
#define AKT 128
__global__ __launch_bounds__(256) void alog_part(
    const float* __restrict__ x, const float* __restrict__ W_in,
    float* __restrict__ P) {
  __shared__ float sX[AR][132];
  __shared__ float sW[32][132];
  const int tid = threadIdx.x;
  const int row0 = blockIdx.x * AR;
  const int k0 = blockIdx.y * 256;
  const int r = tid >> 2;
  const int oq = (tid & 3) * 8;
  float acc[8] = {};
#pragma unroll
  for (int kt = 0; kt < 256; kt += AKT) {
    __syncthreads();
    {
      const int lr = tid >> 2;
      const int kk = (tid & 3) * 32;
      const float* src = x + (size_t)(row0 + lr) * DMODEL + k0 + kt + kk;
      float* dst = &sX[lr][kk];
#pragma unroll
      for (int j = 0; j < 32; j += 4)
        *(f32x4*)(dst + j) = *(const f32x4*)(src + j);
    }
    {
      const int wr = tid >> 3;
      const int kk = (tid & 7) * 16;
      const float* src = W_in + (size_t)(8192 + wr) * DMODEL + k0 + kt + kk;
      float* dst = &sW[wr][kk];
#pragma unroll
      for (int j = 0; j < 16; j += 4)
        *(f32x4*)(dst + j) = *(const f32x4*)(src + j);
    }
    __syncthreads();
#pragma unroll 2
    for (int k = 0; k < AKT; k += 4) {
      f32x4 xv = *(const f32x4*)&sX[r][k];
#pragma unroll
      for (int o = 0; o < 8; ++o) {
        f32x4 wv = *(const f32x4*)&sW[oq + o][k];
        acc[o] = fmaf(xv[0], wv[0], acc[o]);
        acc[o] = fmaf(xv[1], wv[1], acc[o]);
        acc[o] = fmaf(xv[2], wv[2], acc[o]);
        acc[o] = fmaf(xv[3], wv[3], acc[o]);
      }
    }
  }
  float* dst = P + ((size_t)blockIdx.y * 4096 + row0 + r) * 32 + oq;
  f32x4 v0 = {acc[0], acc[1], acc[2], acc[3]};
  f32x4 v1 = {acc[4], acc[5], acc[6], acc[7]};
  *(f32x4*)dst = v0; *(f32x4*)(dst + 4) = v1;
}

__global__ __launch_bounds__(256) void alog_reduce(
    const float* __restrict__ P, float* __restrict__ Alog) {
  const int idx = blockIdx.x * 256 + threadIdx.x;
  const int row = idx >> 5, o = idx & 31;
  float s = 0.f;
#pragma unroll
  for (int c = 0; c < 8; ++c) s += P[((size_t)c * 4096 + row) * 32 + o];
  Alog[(size_t)row * 32 + o] = s;
}

// ---------------- MFMA chunked scan, pass 1 ----------------
__global__ __launch_bounds__(256) void mm_pass1(
    const unsigned short* __restrict__ zx, const float* __restrict__ Alog,
    float* __restrict__ Sfin, float* __restrict__ Dprod) {
  __shared__ uint8_t sXw[16384];
  __shared__ uint8_t sBT[16384];
  __shared__ float logd[128];
  __shared__ float cums[128];
  const int tid = threadIdx.x;
  const int chunk = blockIdx.x;
  const int bh = blockIdx.y;
  const int h = bh & 31, b = bh >> 5;
  const size_t bL0 = (size_t)b * LSEQ + (size_t)chunk * CHUNK;

  if (tid < 128) logd[tid] = -__expf(Alog[(bL0 + tid) * 32 + h]);
  __syncthreads();
  if (tid < 128) {
    float s = 0.f;
#pragma unroll 4
    for (int r = 0; r <= tid; ++r) s += logd[r];
    cums[tid] = s;
  }
  __syncthreads();
  const float clast = cums[127];

  {
    const int u = tid & 127, ph = (tid >> 7) * 32;
    const int half = u >> 6, uk = u & 63;
    const float wfac = __expf(clast - cums[u]);
    const unsigned short* xrow = zx + (bL0 + u) * (size_t)PROJP + h * 64 + ph;
#pragma unroll
    for (int j = 0; j < 4; ++j) {
      u16x8 xv = *(const u16x8*)(xrow + j * 8);
      u16x8 bv = *(const u16x8*)(xrow + 4096 + j * 8);
#pragma unroll
      for (int e = 0; e < 8; ++e) {
        const int p = ph + j * 8 + e;
        const int byteoff = half * 8192 + p * 128 +
                            (((uk >> 3) ^ (p & 7)) << 4) + (uk & 7) * 2;
        *(unsigned short*)(sXw + byteoff) = f2bf(bf2f(xv[e]) * wfac);
        *(unsigned short*)(sBT + byteoff) = bv[e];
      }
    }
  }
  __syncthreads();

  const int lane = tid & 63, w = tid >> 6;
  const int ra = w * 16 + (lane & 15);
  const int s0 = lane >> 4;
  f32x4 acc[4] = {};
#pragma unroll
  for (int half = 0; half < 2; ++half)
#pragma unroll
    for (int ks = 0; ks < 2; ++ks) {
      const int s = ks * 4 + s0;
      bf16x8 af = *(const bf16x8*)(sXw + half * 8192 + ra * 128 + ((s ^ (ra & 7)) << 4));
#pragma unroll
      for (int ni = 0; ni < 4; ++ni) {
        const int rb = ni * 16 + (lane & 15);
        bf16x8 bf = *(const bf16x8*)(sBT + half * 8192 + rb * 128 + ((s ^ (rb & 7)) << 4));
        acc[ni] = __builtin_amdgcn_mfma_f32_16x16x32_bf16(af, bf, acc[ni], 0, 0, 0);
      }
    }

  float* sf = Sfin + ((size_t)bh * NC + chunk) * 4096;
  const int prow = w * 16 + (lane >> 4) * 4;
  const int ncol = lane & 15;
#pragma unroll
  for (int ni = 0; ni < 4; ++ni)
#pragma unroll
    for (int reg = 0; reg < 4; ++reg)
      sf[(size_t)(prow + reg) * 64 + ni * 16 + ncol] = acc[ni][reg];
  if (tid == 0) Dprod[bh * NC + chunk] = __expf(clast);
}

// Combine: exclusive prefix over chunks -> per-chunk initial states.
__global__ __launch_bounds__(256) void scan_combine(
    const float* __restrict__ Sfin, const float* __restrict__ Dp,
    float* __restrict__ Sini) {
  const int idx = blockIdx.x * 256 + threadIdx.x;
  const int bh = idx >> 12;
  const int e = idx & 4095;
  const float* sf = Sfin + (size_t)bh * NC * 4096 + e;
  float* si = Sini + (size_t)bh * NC * 4096 + e;
  float S = 0.f;
#pragma unroll
  for (int c = 0; c < NC; ++c) {
    si[(size_t)c * 4096] = S;
    if (c < NC - 1) S = fmaf(S, Dp[bh * NC + c], sf[(size_t)c * 4096]);
  }
}

// ---------------- MFMA chunked scan, pass 2 ----------------
__global__ __launch_bounds__(256) void mm_pass2(
    const unsigned short* __restrict__ zx, const float* __restrict__ Alog,
    const float* __restrict__ Sini, float* __restrict__ y) {
  __shared__ uint8_t smem[65536];
  __shared__ float logd[128];
  __shared__ float cums[128];
  const int tid = threadIdx.x;
  const int chunk = blockIdx.x;
  const int bh = blockIdx.y;
  const int h = bh & 31, b = bh >> 5;
  const size_t bL0 = (size_t)b * LSEQ + (size_t)chunk * CHUNK;
  const int lane = tid & 63, w = tid >> 6;

  if (tid < 128) logd[tid] = -__expf(Alog[(bL0 + tid) * 32 + h]);
  {
    const int rowS = tid >> 3;
    const int slot = (tid & 7) ^ (rowS & 7);
    const unsigned short* cb = zx + (bL0 + rowS) * (size_t)PROJP + 6144 + h * 64 + slot * 8;
    const unsigned short* bb = zx + (bL0 + rowS) * (size_t)PROJP + 4096 + h * 64 + slot * 8;
    const int dbase = w * 1024;
#pragma unroll
    for (int j = 0; j < 4; ++j) {
      gl_lds16(cb + (size_t)j * 32 * PROJP, smem + dbase + j * 4096);
      gl_lds16(bb + (size_t)j * 32 * PROJP, smem + 16384 + dbase + j * 4096);
    }
  }
  __syncthreads();
  if (tid < 128) {
    float s = 0.f;
#pragma unroll 4
    for (int r = 0; r <= tid; ++r) s += logd[r];
    cums[tid] = s;
  }
  {
    const int u = tid & 127, ph = (tid >> 7) * 32;
    const int half = u >> 6, uk = u & 63;
    const unsigned short* xrow = zx + (bL0 + u) * (size_t)PROJP + h * 64 + ph;
#pragma unroll
    for (int j = 0; j < 4; ++j) {
      u16x8 xv = *(const u16x8*)(xrow + j * 8);
#pragma unroll
      for (int e = 0; e < 8; ++e) {
        const int p = ph + j * 8 + e;
        *(unsigned short*)(smem + 32768 + half * 8192 + p * 128 +
                           (((uk >> 3) ^ (p & 7)) << 4) + (uk & 7) * 2) = xv[e];
      }
    }
  }
  {
    const float* si = Sini + ((size_t)bh * NC + chunk) * 4096 + tid * 16;
    const int p = tid >> 2;
#pragma unroll
    for (int gq = 0; gq < 2; ++gq) {
      u16x8 hv, lv;
#pragma unroll
      for (int e = 0; e < 8; ++e) {
        float v = si[gq * 8 + e];
        unsigned short hu = f2bf(v);
        hv[e] = hu;
        lv[e] = f2bf(v - bf2f(hu));
      }
      const int slotg = (tid & 3) * 2 + gq;
      const int byte_ = p * 128 + ((slotg ^ (p & 7)) << 4);
      *(u16x8*)(smem + 49152 + byte_) = hv;
      *(u16x8*)(smem + 57344 + byte_) = lv;
    }
  }
  __syncthreads();

  const int rl = lane & 15, s0 = lane >> 4;
  const int tb = w * 32;
  f32x4 accG[2][8] = {};
  f32x4 acc2[2][4] = {};
#pragma unroll
  for (int ks = 0; ks < 2; ++ks) {
    const int s = ks * 4 + s0;
    bf16x8 ca[2];
#pragma unroll
    for (int mi = 0; mi < 2; ++mi) {
      const int r = tb + mi * 16 + rl;
      ca[mi] = *(const bf16x8*)(smem + r * 128 + ((s ^ (r & 7)) << 4));
    }
#pragma unroll
    for (int ni = 0; ni < 8; ++ni) {
      const int r = ni * 16 + rl;
      bf16x8 bf = *(const bf16x8*)(smem + 16384 + r * 128 + ((s ^ (r & 7)) << 4));
#pragma unroll
      for (int mi = 0; mi < 2; ++mi)
        accG[mi][ni] = __builtin_amdgcn_mfma_f32_16x16x32_bf16(ca[mi], bf, accG[mi][ni], 0, 0, 0);
    }
#pragma unroll
    for (int ni = 0; ni < 4; ++ni) {
      const int r = ni * 16 + rl;
      bf16x8 sh = *(const bf16x8*)(smem + 49152 + r * 128 + ((s ^ (r & 7)) << 4));
      bf16x8 sl = *(const bf16x8*)(smem + 57344 + r * 128 + ((s ^ (r & 7)) << 4));
#pragma unroll
      for (int mi = 0; mi < 2; ++mi) {
        acc2[mi][ni] = __builtin_amdgcn_mfma_f32_16x16x32_bf16(ca[mi], sh, acc2[mi][ni], 0, 0, 0);
        acc2[mi][ni] = __builtin_amdgcn_mfma_f32_16x16x32_bf16(ca[mi], sl, acc2[mi][ni], 0, 0, 0);
      }
    }
  }
  __syncthreads();

  float ct[2][4];
#pragma unroll
  for (int mi = 0; mi < 2; ++mi)
#pragma unroll
    for (int reg = 0; reg < 4; ++reg)
      ct[mi][reg] = cums[tb + mi * 16 + (lane >> 4) * 4 + reg];
#pragma unroll
  for (int ni = 0; ni < 8; ++ni) {
    const int u = ni * 16 + rl;
    const float cu = cums[u];
    const int Ph = u >> 6, uk = u & 63;
#pragma unroll
    for (int mi = 0; mi < 2; ++mi)
#pragma unroll
      for (int reg = 0; reg < 4; ++reg) {
        const int t = tb + mi * 16 + (lane >> 4) * 4 + reg;
        float v = (u <= t) ? accG[mi][ni][reg] * __expf(ct[mi][reg] - cu) : 0.f;
        *(unsigned short*)(smem + Ph * 16384 + t * 128 +
                           (((uk >> 3) ^ (t & 7)) << 4) + (uk & 7) * 2) = f2bf(v);
      }
  }
  __syncthreads();

  f32x4 accY[2][4] = {};
#pragma unroll
  for (int half = 0; half < 2; ++half)
#pragma unroll
    for (int ks = 0; ks < 2; ++ks) {
      const int s = ks * 4 + s0;
      bf16x8 pa[2];
#pragma unroll
      for (int mi = 0; mi < 2; ++mi) {
        const int r = tb + mi * 16 + rl;
        pa[mi] = *(const bf16x8*)(smem + half * 16384 + r * 128 + ((s ^ (r & 7)) << 4));
      }
#pragma unroll
      for (int ni = 0; ni < 4; ++ni) {
        const int r = ni * 16 + rl;
        bf16x8 xb = *(const bf16x8*)(smem + 32768 + half * 8192 + r * 128 + ((s ^ (r & 7)) << 4));
#pragma unroll
        for (int mi = 0; mi < 2; ++mi)
          accY[mi][ni] = __builtin_amdgcn_mfma_f32_16x16x32_bf16(pa[mi], xb, accY[mi][ni], 0, 0, 0);
      }
    }

#pragma unroll
  for (int mi = 0; mi < 2; ++mi)
#pragma unroll
    for (int reg = 0; reg < 4; ++reg) {
      const int t = tb + mi * 16 + (lane >> 4) * 4 + reg;
      const float wt = __expf(ct[mi][reg]);
#pragma unroll
      for (int ni = 0; ni < 4; ++ni) {
        const int p = ni * 16 + rl;
        y[(bL0 + t) * (size_t)DINNER + h * 64 + p] =
            accY[mi][ni][reg] + wt * acc2[mi][ni][reg];
      }
    }
}

// ---------------- fused (y + D*x)*silu(z) + LayerNorm -> bf16 ----------------
__global__ __launch_bounds__(256) void siluln(
    const float* __restrict__ yin, const unsigned short* __restrict__ zx,
    const float* __restrict__ Dmat,
    const float* __restrict__ gamma, const float* __restrict__ beta,
    unsigned short* __restrict__ out) {
  const int row = blockIdx.x;
  const int tid = threadIdx.x;
  const int lane = tid & 63;
  const int wid = tid >> 6;
  const int col = tid * 8;
  const float* yp = yin + (size_t)row * DINNER + col;
  const unsigned short* zp = zx + (size_t)row * PROJP + DINNER + col;
  const unsigned short* xp = zx + (size_t)row * PROJP + col;
  f32x4 y0 = *(const f32x4*)yp, y1 = *(const f32x4*)(yp + 4);
  u16x8 zv = *(const u16x8*)zp;
  u16x8 xv = *(const u16x8*)xp;
  f32x4 d0 = *(const f32x4*)(Dmat + col), d1 = *(const f32x4*)(Dmat + col + 4);
  float v[8];
#pragma unroll
  for (int i = 0; i < 8; ++i) {
    float z = bf2f(zv[i]);
    float dd = (i < 4) ? d0[i] : d1[i - 4];
    float yy = ((i < 4) ? y0[i] : y1[i - 4]) + bf2f(xv[i]) * dd;
    v[i] = yy * (z / (1.f + __expf(-z)));
  }
  float t1 = 0.f, t2 = 0.f;
#pragma unroll
  for (int i = 0; i < 8; ++i) { t1 += v[i]; t2 += v[i] * v[i]; }
#pragma unroll
  for (int off = 1; off < 64; off <<= 1) {
    t1 += __shfl_xor(t1, off);
    t2 += __shfl_xor(t2, off);
  }
  __shared__ float red[8];
  if (lane == 0) { red[wid] = t1; red[wid + 4] = t2; }
  __syncthreads();
  float ts1 = red[0] + red[1] + red[2] + red[3];
  float ts2 = red[4] + red[5] + red[6] + red[7];
  float mu = ts1 * (1.f / 2048.f);
  float var = ts2 * (1.f / 2048.f) - mu * mu;
  float rs = rsqrtf(var + 1e-5f);
  f32x4 g0 = *(const f32x4*)(gamma + col), g1 = *(const f32x4*)(gamma + col + 4);
  f32x4 b0 = *(const f32x4*)(beta + col),  b1 = *(const f32x4*)(beta + col + 4);
  u16x8 ov;
#pragma unroll
  for (int i = 0; i < 4; ++i)
    ov[i] = f2bf((v[i] - mu) * rs * g0[i] + b0[i]);
#pragma unroll
  for (int i = 0; i < 4; ++i)
    ov[i + 4] = f2bf((v[i + 4] - mu) * rs * g1[i] + b1[i]);
  *(u16x8*)(out + (size_t)row * DINNER + col) = ov;
}

// ---------------- launch ----------------
extern "C" void kernel_launch(void* const* d_in, const int* in_sizes, int n_in,
                              void* d_out, int out_size, void* d_ws, size_t ws_size,
                              hipStream_t stream) {
  (void)in_sizes; (void)n_in; (void)out_size; (void)ws_size;
  const float* x     = (const float*)d_in[0];
  const float* W_in  = (const float*)d_in[1];
  const float* W_out = (const float*)d_in[2];
  const float* gamma = (const float*)d_in[3];
  const float* beta  = (const float*)d_in[4];
  const float* Dmat  = (const float*)d_in[5];

  uint8_t* ws = (uint8_t*)d_ws;
  unsigned short* xbf = (unsigned short*)ws;                 // 16 MB; later y_ln
  unsigned short* wbf = (unsigned short*)(ws + 16777216);    // 34 MB region (W)
  float* Palog = (float*)(ws + 16777216);                    // 4 MB
  float* Sfin  = (float*)(ws + 16777216);                    // 16.78 MB (after alog)
  float* Sini  = (float*)(ws + 33554432);                    // 16.78 MB
  float* Dprod = (float*)(ws + 50331648);                    // 4 KB
  float* Alog  = (float*)(ws + 50855936);                    // 512 KB
  unsigned short* zxb = (unsigned short*)(ws + 51380224);    // 64 MB (bf16, stride 8192)
  float* ybuf = (float*)(ws + 119537664);                    // 33.6 MB

  cvt_f32_bf16<<<8192, 256, 0, stream>>>(x, xbf, 8388608);
  cvt_f32_bf16<<<16384, 256, 0, stream>>>(W_in, wbf, 16777216);
  gemm256<<<512, 512, 0, stream>>>(xbf, wbf, zxb, 2048, PROJP, 32);
  alog_part<<<dim3(64, 8), 256, 0, stream>>>(x, W_in, Palog);
  alog_reduce<<<512, 256, 0, stream>>>(Palog, Alog);
  mm_pass1<<<dim3(NC - 1, 64), 256, 0, stream>>>(zxb, Alog, Sfin, Dprod);
  scan_combine<<<1024, 256, 0, stream>>>(Sfin, Dprod, Sini);
  mm_pass2<<<dim3(NC, 64), 256, 0, stream>>>(zxb, Alog, Sini, ybuf);
  siluln<<<4096, 256, 0, stream>>>(ybuf, zxb, Dmat, gamma, beta, xbf);
  cvt_f32_bf16<<<4096, 256, 0, stream>>>(W_out, wbf, 4194304);
  gemm_bt<<<512, 256, 0, stream>>>(xbf, wbf, (float*)d_out, 2048, 2048, 16);
}

// Round 14
// 287.239 us; speedup vs baseline: 1.2924x; 1.2924x over previous
//
#include <hip/hip_runtime.h>
#include <stdint.h>
#include <stddef.h>

#define LSEQ   2048
#define DMODEL 2048
#define NH     32
#define DINNER 2048
#define PROJ   8224
#define PROJP  8192   // bf16 GEMM width: x,z,b,c only (a_log handled in fp32)
#define NC     16     // scan chunks
#define CHUNK  128    // LSEQ / NC

typedef __attribute__((ext_vector_type(4))) float f32x4;
typedef __attribute__((ext_vector_type(8))) __bf16 bf16x8;
typedef __attribute__((ext_vector_type(8))) unsigned short u16x8;

__device__ __forceinline__ unsigned short f2bf(float f) {
  union { float f; unsigned u; } uu; uu.f = f;
  unsigned r = uu.u + 0x7FFFu + ((uu.u >> 16) & 1u);
  return (unsigned short)(r >> 16);
}
__device__ __forceinline__ float bf2f(unsigned short u) {
  union { unsigned u; float f; } x; x.u = ((unsigned)u) << 16; return x.f;
}

__device__ __forceinline__ void gl_lds16(const void* g, void* l) {
  __builtin_amdgcn_global_load_lds(
      (__attribute__((address_space(1))) const void*)g,
      (__attribute__((address_space(3))) void*)l, 16, 0, 0);
}

// ---------------- conversions ----------------
__global__ __launch_bounds__(256) void cvt_f32_bf16(
    const float* __restrict__ in, unsigned short* __restrict__ out, int n) {
  int i = (blockIdx.x * 256 + threadIdx.x) * 4;
  if (i + 3 < n) {
    f32x4 v = *(const f32x4*)(in + i);
    ushort4 o;
    o.x = f2bf(v[0]); o.y = f2bf(v[1]); o.z = f2bf(v[2]); o.w = f2bf(v[3]);
    *(ushort4*)(out + i) = o;
  }
}

// ---------------- 256x256 bf16 NT GEMM, BK=64, 4-phase-per-tile (r10-VERIFIED, 140us) ----
__global__ __launch_bounds__(512, 2) void gemm256(
    const unsigned short* __restrict__ A,
    const unsigned short* __restrict__ W,
    unsigned short* __restrict__ C, const int K, const int ldc, const int ntx) {
  __shared__ uint8_t sA[2][32768];
  __shared__ uint8_t sB[2][32768];
  const int tid  = threadIdx.x;
  const int lane = tid & 63;
  const int wid  = tid >> 6;
  const int wm   = wid >> 2;
  const int wnn  = wid & 3;
  const int nwg = gridDim.x;
  const int wg0 = blockIdx.x;
  const int g   = (wg0 & 7) * (nwg >> 3) + (wg0 >> 3);
  const int grp = ntx * 4;
  const int sr  = g / grp, rem = g % grp;
  const int m0  = (sr * 4 + (rem & 3)) * 256;
  const int n0  = (rem >> 2) * 256;

  const int row0 = wid * 8 + (lane >> 3);
  const int ssrc = (lane & 7) ^ (row0 & 7);
  const unsigned short* a_base = A + (size_t)(m0 + row0) * K + ssrc * 8;
  const unsigned short* b_base = W + (size_t)(n0 + row0) * K + ssrc * 8;
  const int wb = wid * 1024;

  f32x4 acc[8][4] = {};
  const int nk = K >> 6;

#pragma unroll
  for (int j = 0; j < 4; ++j) {
    gl_lds16(a_base + (size_t)j * 64 * K, &sA[0][j * 8192 + wb]);
    gl_lds16(b_base + (size_t)j * 64 * K, &sB[0][j * 8192 + wb]);
  }
  asm volatile("s_waitcnt vmcnt(0)" ::: "memory");
  asm volatile("s_barrier" ::: "memory");

  const int ra = wm * 128 + (lane & 15);
  const int rb = wnn * 64 + (lane & 15);
  const int hq = lane >> 4;

  for (int kt = 0; kt < nk; ++kt) {
    const int cur = kt & 1;
    const int nxt = cur ^ 1;
    const unsigned short* an = a_base + (size_t)(kt + 1) * 64;
    const unsigned short* wn_ = b_base + (size_t)(kt + 1) * 64;
    bf16x8 af[8], bv01[2], bv23[2];

    // ---- P0: af@ks0 + bv01@ks0; stage A/B rows 0-127 of tile kt+1 ----
    {
      const int s = hq;
#pragma unroll
      for (int mi = 0; mi < 8; ++mi) {
        const int r = ra + mi * 16;
        af[mi] = *(const bf16x8*)(&sA[cur][r * 128 + ((s ^ (r & 7)) << 4)]);
      }
#pragma unroll
      for (int ni = 0; ni < 2; ++ni) {
        const int r = rb + ni * 16;
        bv01[ni] = *(const bf16x8*)(&sB[cur][r * 128 + ((s ^ (r & 7)) << 4)]);
      }
    }
    if (kt + 1 < nk) {
      gl_lds16(an, &sA[nxt][wb]);
      gl_lds16(an + (size_t)64 * K, &sA[nxt][8192 + wb]);
      gl_lds16(wn_, &sB[nxt][wb]);
      gl_lds16(wn_ + (size_t)64 * K, &sB[nxt][8192 + wb]);
    }
    asm volatile("s_barrier" ::: "memory");
    asm volatile("s_waitcnt lgkmcnt(0)" ::: "memory");
    __builtin_amdgcn_s_setprio(1);
#pragma unroll
    for (int mi = 0; mi < 8; ++mi)
#pragma unroll
      for (int ni = 0; ni < 2; ++ni)
        acc[mi][ni] = __builtin_amdgcn_mfma_f32_16x16x32_bf16(
            af[mi], bv01[ni], acc[mi][ni], 0, 0, 0);
    __builtin_amdgcn_s_setprio(0);
    asm volatile("s_barrier" ::: "memory");

    // ---- P1: bv23@ks0; stage A/B rows 128-255 of tile kt+1 ----
    {
      const int s = hq;
#pragma unroll
      for (int ni = 0; ni < 2; ++ni) {
        const int r = rb + (ni + 2) * 16;
        bv23[ni] = *(const bf16x8*)(&sB[cur][r * 128 + ((s ^ (r & 7)) << 4)]);
      }
    }
    if (kt + 1 < nk) {
      gl_lds16(an + (size_t)128 * K, &sA[nxt][2 * 8192 + wb]);
      gl_lds16(an + (size_t)192 * K, &sA[nxt][3 * 8192 + wb]);
      gl_lds16(wn_ + (size_t)128 * K, &sB[nxt][2 * 8192 + wb]);
      gl_lds16(wn_ + (size_t)192 * K, &sB[nxt][3 * 8192 + wb]);
    }
    asm volatile("s_barrier" ::: "memory");
    asm volatile("s_waitcnt lgkmcnt(0)" ::: "memory");
    __builtin_amdgcn_s_setprio(1);
#pragma unroll
    for (int mi = 0; mi < 8; ++mi)
#pragma unroll
      for (int ni = 0; ni < 2; ++ni)
        acc[mi][ni + 2] = __builtin_amdgcn_mfma_f32_16x16x32_bf16(
            af[mi], bv23[ni], acc[mi][ni + 2], 0, 0, 0);
    __builtin_amdgcn_s_setprio(0);
    asm volatile("s_barrier" ::: "memory");

    // ---- P2: af@ks1 + bv01@ks1 ----
    {
      const int s = 4 + hq;
#pragma unroll
      for (int mi = 0; mi < 8; ++mi) {
        const int r = ra + mi * 16;
        af[mi] = *(const bf16x8*)(&sA[cur][r * 128 + ((s ^ (r & 7)) << 4)]);
      }
#pragma unroll
      for (int ni = 0; ni < 2; ++ni) {
        const int r = rb + ni * 16;
        bv01[ni] = *(const bf16x8*)(&sB[cur][r * 128 + ((s ^ (r & 7)) << 4)]);
      }
    }
    asm volatile("s_barrier" ::: "memory");
    asm volatile("s_waitcnt lgkmcnt(0)" ::: "memory");
    __builtin_amdgcn_s_setprio(1);
#pragma unroll
    for (int mi = 0; mi < 8; ++mi)
#pragma unroll
      for (int ni = 0; ni < 2; ++ni)
        acc[mi][ni] = __builtin_amdgcn_mfma_f32_16x16x32_bf16(
            af[mi], bv01[ni], acc[mi][ni], 0, 0, 0);
    __builtin_amdgcn_s_setprio(0);
    asm volatile("s_barrier" ::: "memory");

    // ---- P3: bv23@ks1 ----
    {
      const int s = 4 + hq;
#pragma unroll
      for (int ni = 0; ni < 2; ++ni) {
        const int r = rb + (ni + 2) * 16;
        bv23[ni] = *(const bf16x8*)(&sB[cur][r * 128 + ((s ^ (r & 7)) << 4)]);
      }
    }
    asm volatile("s_barrier" ::: "memory");
    asm volatile("s_waitcnt lgkmcnt(0)" ::: "memory");
    __builtin_amdgcn_s_setprio(1);
#pragma unroll
    for (int mi = 0; mi < 8; ++mi)
#pragma unroll
      for (int ni = 0; ni < 2; ++ni)
        acc[mi][ni + 2] = __builtin_amdgcn_mfma_f32_16x16x32_bf16(
            af[mi], bv23[ni], acc[mi][ni + 2], 0, 0, 0);
    __builtin_amdgcn_s_setprio(0);
    asm volatile("s_waitcnt vmcnt(0)" ::: "memory");
    asm volatile("s_barrier" ::: "memory");
  }

  const int crow = m0 + wm * 128 + (lane >> 4) * 4;
  const int ccol = n0 + wnn * 64 + (lane & 15);
#pragma unroll
  for (int mi = 0; mi < 8; ++mi)
#pragma unroll
    for (int ni = 0; ni < 4; ++ni) {
      unsigned short* cp = C + (size_t)(crow + mi * 16) * ldc + ccol + ni * 16;
      cp[0] = f2bf(acc[mi][ni][0]);
      cp[(size_t)ldc] = f2bf(acc[mi][ni][1]);
      cp[2 * (size_t)ldc] = f2bf(acc[mi][ni][2]);
      cp[3 * (size_t)ldc] = f2bf(acc[mi][ni][3]);
    }
}

// ---------------- 128x128 bf16 NT GEMM (gemm2), single-barrier loop ----------------
__global__ __launch_bounds__(256) void gemm_bt(
    const unsigned short* __restrict__ A,
    const unsigned short* __restrict__ W,
    float* __restrict__ C, const int K, const int ldc, const int ntx) {
  __shared__ uint8_t sA[2][128 * 64 * 2];
  __shared__ uint8_t sB[2][128 * 64 * 2];
  const int tid  = threadIdx.x;
  const int lane = tid & 63;
  const int wid  = tid >> 6;
  const int wm   = wid >> 1;
  const int wnn  = wid & 1;
  const int nwg = gridDim.x;
  const int wg0 = blockIdx.x;
  const int g   = (wg0 & 7) * (nwg >> 3) + (wg0 >> 3);
  const int grp = ntx * 4;
  const int sr  = g / grp, rem = g % grp;
  const int m0  = (sr * 4 + (rem & 3)) * 128;
  const int n0  = (rem >> 2) * 128;

  const int rowA = tid >> 3;
  const int slot = (tid & 7) ^ (rowA & 7);
  const unsigned short* a_base = A + (size_t)(m0 + rowA) * K + slot * 8;
  const unsigned short* b_base = W + (size_t)(n0 + rowA) * K + slot * 8;
  const int loff = wid * 1024;

  f32x4 acc[4][4] = {};
  const int nk = K >> 6;

#pragma unroll
  for (int j = 0; j < 4; ++j) {
    gl_lds16(a_base + (size_t)j * 32 * K, &sA[0][loff + j * 4096]);
    gl_lds16(b_base + (size_t)j * 32 * K, &sB[0][loff + j * 4096]);
  }

  for (int kt = 0; kt < nk; ++kt) {
    const int cur = kt & 1;
    asm volatile("s_waitcnt vmcnt(0)" ::: "memory");
    asm volatile("s_barrier" ::: "memory");
    if (kt + 1 < nk) {
      const unsigned short* ak = a_base + (kt + 1) * 64;
      const unsigned short* bk = b_base + (kt + 1) * 64;
      const int nb = cur ^ 1;
#pragma unroll
      for (int j = 0; j < 4; ++j) {
        gl_lds16(ak + (size_t)j * 32 * K, &sA[nb][loff + j * 4096]);
        gl_lds16(bk + (size_t)j * 32 * K, &sB[nb][loff + j * 4096]);
      }
    }

    const int ra = wm * 64 + (lane & 15);
    const int rb = wnn * 64 + (lane & 15);
    const int hq = lane >> 4;
#pragma unroll
    for (int ks = 0; ks < 2; ++ks) {
      bf16x8 af[4], bv[4];
      const int s = ks * 4 + hq;
#pragma unroll
      for (int mi = 0; mi < 4; ++mi) {
        const int r = ra + mi * 16;
        af[mi] = *(const bf16x8*)(&sA[cur][r * 128 + ((s ^ (r & 7)) << 4)]);
      }
#pragma unroll
      for (int ni = 0; ni < 4; ++ni) {
        const int r = rb + ni * 16;
        bv[ni] = *(const bf16x8*)(&sB[cur][r * 128 + ((s ^ (r & 7)) << 4)]);
      }
#pragma unroll
      for (int mi = 0; mi < 4; ++mi)
#pragma unroll
        for (int ni = 0; ni < 4; ++ni)
          acc[mi][ni] = __builtin_amdgcn_mfma_f32_16x16x32_bf16(
              af[mi], bv[ni], acc[mi][ni], 0, 0, 0);
    }
  }

  const int crow = m0 + wm * 64 + (lane >> 4) * 4;
  const int ccol = n0 + wnn * 64 + (lane & 15);
#pragma unroll
  for (int mi = 0; mi < 4; ++mi)
#pragma unroll
    for (int ni = 0; ni < 4; ++ni) {
      float* cp = C + (size_t)(crow + mi * 16) * ldc + ccol + ni * 16;
      cp[0] = acc[mi][ni][0];
      cp[(size_t)ldc] = acc[mi][ni][1];
      cp[2 * (size_t)ldc] = acc[mi][ni][2];
      cp[3 * (size_t)ldc] = acc[mi][ni][3];
    }
}

// ---------------- exact fp32 a_log slab + fused x->bf16 emit ----------------
// Each block covers rows row0..+64, cols k0+kt..+128 of x exactly once across
// the grid -> also emits xbf for those elements (replaces the cvt_x kernel).
#define AR  64
#define AKT 128
__global__ __launch_bounds__(256) void alog_part(
    const float* __restrict__ x, const float* __restrict__ W_in,
    float* __restrict__ P, unsigned short* __restrict__ xbf) {
  __shared__ float sX[AR][132];
  __shared__ float sW[32][132];
  const int tid = threadIdx.x;
  const int row0 = blockIdx.x * AR;
  const int k0 = blockIdx.y * 256;
  const int r = tid >> 2;
  const int oq = (tid & 3) * 8;
  float acc[8] = {};
#pragma unroll
  for (int kt = 0; kt < 256; kt += AKT) {
    __syncthreads();
    {
      const int lr = tid >> 2;
      const int kk = (tid & 3) * 32;
      const float* src = x + (size_t)(row0 + lr) * DMODEL + k0 + kt + kk;
      float* dst = &sX[lr][kk];
      unsigned short* xb = xbf + (size_t)(row0 + lr) * DMODEL + k0 + kt + kk;
#pragma unroll
      for (int j = 0; j < 32; j += 4) {
        f32x4 v = *(const f32x4*)(src + j);
        *(f32x4*)(dst + j) = v;
        ushort4 o;
        o.x = f2bf(v[0]); o.y = f2bf(v[1]); o.z = f2bf(v[2]); o.w = f2bf(v[3]);
        *(ushort4*)(xb + j) = o;
      }
    }
    {
      const int wr = tid >> 3;
      const int kk = (tid & 7) * 16;
      const float* src = W_in + (size_t)(8192 + wr) * DMODEL + k0 + kt + kk;
      float* dst = &sW[wr][kk];
#pragma unroll
      for (int j = 0; j < 16; j += 4)
        *(f32x4*)(dst + j) = *(const f32x4*)(src + j);
    }
    __syncthreads();
#pragma unroll 2
    for (int k = 0; k < AKT; k += 4) {
      f32x4 xv = *(const f32x4*)&sX[r][k];
#pragma unroll
      for (int o = 0; o < 8; ++o) {
        f32x4 wv = *(const f32x4*)&sW[oq + o][k];
        acc[o] = fmaf(xv[0], wv[0], acc[o]);
        acc[o] = fmaf(xv[1], wv[1], acc[o]);
        acc[o] = fmaf(xv[2], wv[2], acc[o]);
        acc[o] = fmaf(xv[3], wv[3], acc[o]);
      }
    }
  }
  float* dst = P + ((size_t)blockIdx.y * 4096 + row0 + r) * 32 + oq;
  f32x4 v0 = {acc[0], acc[1], acc[2], acc[3]};
  f32x4 v1 = {acc[4], acc[5], acc[6], acc[7]};
  *(f32x4*)dst = v0; *(f32x4*)(dst + 4) = v1;
}

__global__ __launch_bounds__(256) void alog_reduce(
    const float* __restrict__ P, float* __restrict__ Alog) {
  const int idx = blockIdx.x * 256 + threadIdx.x;
  const int row = idx >> 5, o = idx & 31;
  float s = 0.f;
#pragma unroll
  for (int c = 0; c < 8; ++c) s += P[((size_t)c * 4096 + row) * 32 + o];
  Alog[(size_t)row * 32 + o] = s;
}

// ---------------- MFMA chunked scan, pass 1 ----------------
__global__ __launch_bounds__(256) void mm_pass1(
    const unsigned short* __restrict__ zx, const float* __restrict__ Alog,
    float* __restrict__ Sfin, float* __restrict__ Dprod) {
  __shared__ uint8_t sXw[16384];
  __shared__ uint8_t sBT[16384];
  __shared__ float logd[128];
  __shared__ float cums[128];
  const int tid = threadIdx.x;
  const int chunk = blockIdx.x;
  const int bh = blockIdx.y;
  const int h = bh & 31, b = bh >> 5;
  const size_t bL0 = (size_t)b * LSEQ + (size_t)chunk * CHUNK;

  if (tid < 128) logd[tid] = -__expf(Alog[(bL0 + tid) * 32 + h]);
  __syncthreads();
  if (tid < 128) {
    float s = 0.f;
#pragma unroll 4
    for (int r = 0; r <= tid; ++r) s += logd[r];
    cums[tid] = s;
  }
  __syncthreads();
  const float clast = cums[127];

  {
    const int u = tid & 127, ph = (tid >> 7) * 32;
    const int half = u >> 6, uk = u & 63;
    const float wfac = __expf(clast - cums[u]);
    const unsigned short* xrow = zx + (bL0 + u) * (size_t)PROJP + h * 64 + ph;
#pragma unroll
    for (int j = 0; j < 4; ++j) {
      u16x8 xv = *(const u16x8*)(xrow + j * 8);
      u16x8 bv = *(const u16x8*)(xrow + 4096 + j * 8);
#pragma unroll
      for (int e = 0; e < 8; ++e) {
        const int p = ph + j * 8 + e;
        const int byteoff = half * 8192 + p * 128 +
                            (((uk >> 3) ^ (p & 7)) << 4) + (uk & 7) * 2;
        *(unsigned short*)(sXw + byteoff) = f2bf(bf2f(xv[e]) * wfac);
        *(unsigned short*)(sBT + byteoff) = bv[e];
      }
    }
  }
  __syncthreads();

  const int lane = tid & 63, w = tid >> 6;
  const int ra = w * 16 + (lane & 15);
  const int s0 = lane >> 4;
  f32x4 acc[4] = {};
#pragma unroll
  for (int half = 0; half < 2; ++half)
#pragma unroll
    for (int ks = 0; ks < 2; ++ks) {
      const int s = ks * 4 + s0;
      bf16x8 af = *(const bf16x8*)(sXw + half * 8192 + ra * 128 + ((s ^ (ra & 7)) << 4));
#pragma unroll
      for (int ni = 0; ni < 4; ++ni) {
        const int rb = ni * 16 + (lane & 15);
        bf16x8 bf = *(const bf16x8*)(sBT + half * 8192 + rb * 128 + ((s ^ (rb & 7)) << 4));
        acc[ni] = __builtin_amdgcn_mfma_f32_16x16x32_bf16(af, bf, acc[ni], 0, 0, 0);
      }
    }

  float* sf = Sfin + ((size_t)bh * NC + chunk) * 4096;
  const int prow = w * 16 + (lane >> 4) * 4;
  const int ncol = lane & 15;
#pragma unroll
  for (int ni = 0; ni < 4; ++ni)
#pragma unroll
    for (int reg = 0; reg < 4; ++reg)
      sf[(size_t)(prow + reg) * 64 + ni * 16 + ncol] = acc[ni][reg];
  if (tid == 0) Dprod[bh * NC + chunk] = __expf(clast);
}

// Combine: exclusive prefix over chunks -> per-chunk initial states.
__global__ __launch_bounds__(256) void scan_combine(
    const float* __restrict__ Sfin, const float* __restrict__ Dp,
    float* __restrict__ Sini) {
  const int idx = blockIdx.x * 256 + threadIdx.x;
  const int bh = idx >> 12;
  const int e = idx & 4095;
  const float* sf = Sfin + (size_t)bh * NC * 4096 + e;
  float* si = Sini + (size_t)bh * NC * 4096 + e;
  float S = 0.f;
#pragma unroll
  for (int c = 0; c < NC; ++c) {
    si[(size_t)c * 4096] = S;
    if (c < NC - 1) S = fmaf(S, Dp[bh * NC + c], sf[(size_t)c * 4096]);
  }
}

// ---------------- MFMA chunked scan, pass 2 ----------------
__global__ __launch_bounds__(256) void mm_pass2(
    const unsigned short* __restrict__ zx, const float* __restrict__ Alog,
    const float* __restrict__ Sini, float* __restrict__ y) {
  __shared__ uint8_t smem[65536];
  __shared__ float logd[128];
  __shared__ float cums[128];
  const int tid = threadIdx.x;
  const int chunk = blockIdx.x;
  const int bh = blockIdx.y;
  const int h = bh & 31, b = bh >> 5;
  const size_t bL0 = (size_t)b * LSEQ + (size_t)chunk * CHUNK;
  const int lane = tid & 63, w = tid >> 6;

  if (tid < 128) logd[tid] = -__expf(Alog[(bL0 + tid) * 32 + h]);
  {
    const int rowS = tid >> 3;
    const int slot = (tid & 7) ^ (rowS & 7);
    const unsigned short* cb = zx + (bL0 + rowS) * (size_t)PROJP + 6144 + h * 64 + slot * 8;
    const unsigned short* bb = zx + (bL0 + rowS) * (size_t)PROJP + 4096 + h * 64 + slot * 8;
    const int dbase = w * 1024;
#pragma unroll
    for (int j = 0; j < 4; ++j) {
      gl_lds16(cb + (size_t)j * 32 * PROJP, smem + dbase + j * 4096);
      gl_lds16(bb + (size_t)j * 32 * PROJP, smem + 16384 + dbase + j * 4096);
    }
  }
  __syncthreads();
  if (tid < 128) {
    float s = 0.f;
#pragma unroll 4
    for (int r = 0; r <= tid; ++r) s += logd[r];
    cums[tid] = s;
  }
  {
    const int u = tid & 127, ph = (tid >> 7) * 32;
    const int half = u >> 6, uk = u & 63;
    const unsigned short* xrow = zx + (bL0 + u) * (size_t)PROJP + h * 64 + ph;
#pragma unroll
    for (int j = 0; j < 4; ++j) {
      u16x8 xv = *(const u16x8*)(xrow + j * 8);
#pragma unroll
      for (int e = 0; e < 8; ++e) {
        const int p = ph + j * 8 + e;
        *(unsigned short*)(smem + 32768 + half * 8192 + p * 128 +
                           (((uk >> 3) ^ (p & 7)) << 4) + (uk & 7) * 2) = xv[e];
      }
    }
  }
  {
    const float* si = Sini + ((size_t)bh * NC + chunk) * 4096 + tid * 16;
    const int p = tid >> 2;
#pragma unroll
    for (int gq = 0; gq < 2; ++gq) {
      u16x8 hv, lv;
#pragma unroll
      for (int e = 0; e < 8; ++e) {
        float v = si[gq * 8 + e];
        unsigned short hu = f2bf(v);
        hv[e] = hu;
        lv[e] = f2bf(v - bf2f(hu));
      }
      const int slotg = (tid & 3) * 2 + gq;
      const int byte_ = p * 128 + ((slotg ^ (p & 7)) << 4);
      *(u16x8*)(smem + 49152 + byte_) = hv;
      *(u16x8*)(smem + 57344 + byte_) = lv;
    }
  }
  __syncthreads();

  const int rl = lane & 15, s0 = lane >> 4;
  const int tb = w * 32;
  f32x4 accG[2][8] = {};
  f32x4 acc2[2][4] = {};
#pragma unroll
  for (int ks = 0; ks < 2; ++ks) {
    const int s = ks * 4 + s0;
    bf16x8 ca[2];
#pragma unroll
    for (int mi = 0; mi < 2; ++mi) {
      const int r = tb + mi * 16 + rl;
      ca[mi] = *(const bf16x8*)(smem + r * 128 + ((s ^ (r & 7)) << 4));
    }
#pragma unroll
    for (int ni = 0; ni < 8; ++ni) {
      const int r = ni * 16 + rl;
      bf16x8 bf = *(const bf16x8*)(smem + 16384 + r * 128 + ((s ^ (r & 7)) << 4));
#pragma unroll
      for (int mi = 0; mi < 2; ++mi)
        accG[mi][ni] = __builtin_amdgcn_mfma_f32_16x16x32_bf16(ca[mi], bf, accG[mi][ni], 0, 0, 0);
    }
#pragma unroll
    for (int ni = 0; ni < 4; ++ni) {
      const int r = ni * 16 + rl;
      bf16x8 sh = *(const bf16x8*)(smem + 49152 + r * 128 + ((s ^ (r & 7)) << 4));
      bf16x8 sl = *(const bf16x8*)(smem + 57344 + r * 128 + ((s ^ (r & 7)) << 4));
#pragma unroll
      for (int mi = 0; mi < 2; ++mi) {
        acc2[mi][ni] = __builtin_amdgcn_mfma_f32_16x16x32_bf16(ca[mi], sh, acc2[mi][ni], 0, 0, 0);
        acc2[mi][ni] = __builtin_amdgcn_mfma_f32_16x16x32_bf16(ca[mi], sl, acc2[mi][ni], 0, 0, 0);
      }
    }
  }
  __syncthreads();

  float ct[2][4];
#pragma unroll
  for (int mi = 0; mi < 2; ++mi)
#pragma unroll
    for (int reg = 0; reg < 4; ++reg)
      ct[mi][reg] = cums[tb + mi * 16 + (lane >> 4) * 4 + reg];
#pragma unroll
  for (int ni = 0; ni < 8; ++ni) {
    const int u = ni * 16 + rl;
    const float cu = cums[u];
    const int Ph = u >> 6, uk = u & 63;
#pragma unroll
    for (int mi = 0; mi < 2; ++mi)
#pragma unroll
      for (int reg = 0; reg < 4; ++reg) {
        const int t = tb + mi * 16 + (lane >> 4) * 4 + reg;
        float v = (u <= t) ? accG[mi][ni][reg] * __expf(ct[mi][reg] - cu) : 0.f;
        *(unsigned short*)(smem + Ph * 16384 + t * 128 +
                           (((uk >> 3) ^ (t & 7)) << 4) + (uk & 7) * 2) = f2bf(v);
      }
  }
  __syncthreads();

  f32x4 accY[2][4] = {};
#pragma unroll
  for (int half = 0; half < 2; ++half)
#pragma unroll
    for (int ks = 0; ks < 2; ++ks) {
      const int s = ks * 4 + s0;
      bf16x8 pa[2];
#pragma unroll
      for (int mi = 0; mi < 2; ++mi) {
        const int r = tb + mi * 16 + rl;
        pa[mi] = *(const bf16x8*)(smem + half * 16384 + r * 128 + ((s ^ (r & 7)) << 4));
      }
#pragma unroll
      for (int ni = 0; ni < 4; ++ni) {
        const int r = ni * 16 + rl;
        bf16x8 xb = *(const bf16x8*)(smem + 32768 + half * 8192 + r * 128 + ((s ^ (r & 7)) << 4));
#pragma unroll
        for (int mi = 0; mi < 2; ++mi)
          accY[mi][ni] = __builtin_amdgcn_mfma_f32_16x16x32_bf16(pa[mi], xb, accY[mi][ni], 0, 0, 0);
      }
    }

#pragma unroll
  for (int mi = 0; mi < 2; ++mi)
#pragma unroll
    for (int reg = 0; reg < 4; ++reg) {
      const int t = tb + mi * 16 + (lane >> 4) * 4 + reg;
      const float wt = __expf(ct[mi][reg]);
#pragma unroll
      for (int ni = 0; ni < 4; ++ni) {
        const int p = ni * 16 + rl;
        y[(bL0 + t) * (size_t)DINNER + h * 64 + p] =
            accY[mi][ni][reg] + wt * acc2[mi][ni][reg];
      }
    }
}

// ---------------- fused (y + D*x)*silu(z) + LayerNorm -> bf16 ----------------
__global__ __launch_bounds__(256) void siluln(
    const float* __restrict__ yin, const unsigned short* __restrict__ zx,
    const float* __restrict__ Dmat,
    const float* __restrict__ gamma, const float* __restrict__ beta,
    unsigned short* __restrict__ out) {
  const int row = blockIdx.x;
  const int tid = threadIdx.x;
  const int lane = tid & 63;
  const int wid = tid >> 6;
  const int col = tid * 8;
  const float* yp = yin + (size_t)row * DINNER + col;
  const unsigned short* zp = zx + (size_t)row * PROJP + DINNER + col;
  const unsigned short* xp = zx + (size_t)row * PROJP + col;
  f32x4 y0 = *(const f32x4*)yp, y1 = *(const f32x4*)(yp + 4);
  u16x8 zv = *(const u16x8*)zp;
  u16x8 xv = *(const u16x8*)xp;
  f32x4 d0 = *(const f32x4*)(Dmat + col), d1 = *(const f32x4*)(Dmat + col + 4);
  float v[8];
#pragma unroll
  for (int i = 0; i < 8; ++i) {
    float z = bf2f(zv[i]);
    float dd = (i < 4) ? d0[i] : d1[i - 4];
    float yy = ((i < 4) ? y0[i] : y1[i - 4]) + bf2f(xv[i]) * dd;
    v[i] = yy * (z / (1.f + __expf(-z)));
  }
  float t1 = 0.f, t2 = 0.f;
#pragma unroll
  for (int i = 0; i < 8; ++i) { t1 += v[i]; t2 += v[i] * v[i]; }
#pragma unroll
  for (int off = 1; off < 64; off <<= 1) {
    t1 += __shfl_xor(t1, off);
    t2 += __shfl_xor(t2, off);
  }
  __shared__ float red[8];
  if (lane == 0) { red[wid] = t1; red[wid + 4] = t2; }
  __syncthreads();
  float ts1 = red[0] + red[1] + red[2] + red[3];
  float ts2 = red[4] + red[5] + red[6] + red[7];
  float mu = ts1 * (1.f / 2048.f);
  float var = ts2 * (1.f / 2048.f) - mu * mu;
  float rs = rsqrtf(var + 1e-5f);
  f32x4 g0 = *(const f32x4*)(gamma + col), g1 = *(const f32x4*)(gamma + col + 4);
  f32x4 b0 = *(const f32x4*)(beta + col),  b1 = *(const f32x4*)(beta + col + 4);
  u16x8 ov;
#pragma unroll
  for (int i = 0; i < 4; ++i)
    ov[i] = f2bf((v[i] - mu) * rs * g0[i] + b0[i]);
#pragma unroll
  for (int i = 0; i < 4; ++i)
    ov[i + 4] = f2bf((v[i + 4] - mu) * rs * g1[i] + b1[i]);
  *(u16x8*)(out + (size_t)row * DINNER + col) = ov;
}

// ---------------- launch ----------------
extern "C" void kernel_launch(void* const* d_in, const int* in_sizes, int n_in,
                              void* d_out, int out_size, void* d_ws, size_t ws_size,
                              hipStream_t stream) {
  (void)in_sizes; (void)n_in; (void)out_size; (void)ws_size;
  const float* x     = (const float*)d_in[0];
  const float* W_in  = (const float*)d_in[1];
  const float* W_out = (const float*)d_in[2];
  const float* gamma = (const float*)d_in[3];
  const float* beta  = (const float*)d_in[4];
  const float* Dmat  = (const float*)d_in[5];

  uint8_t* ws = (uint8_t*)d_ws;
  unsigned short* xbf = (unsigned short*)ws;                 // 16 MB; later y_ln
  unsigned short* wbf = (unsigned short*)(ws + 16777216);    // 34 MB region (W)
  float* Palog = (float*)(ws + 16777216);                    // 4 MB -- NOTE: overlaps wbf region?
  float* Sfin  = (float*)(ws + 16777216);                    // reused after alog
  float* Sini  = (float*)(ws + 33554432);
  float* Dprod = (float*)(ws + 50331648);
  float* Alog  = (float*)(ws + 50855936);                    // 512 KB
  unsigned short* zxb = (unsigned short*)(ws + 51380224);    // 64 MB (bf16, stride 8192)
  float* ybuf = (float*)(ws + 119537664);                    // 33.6 MB
  // Palog/Sfin share [ws+16MB, ws+33MB) with wbf's W_in image; W_in bf16 is
  // only needed by gemm256, so alog partials must use a region not clobbering
  // wbf until gemm256 done. Use ybuf (dead until mm_pass2) for Palog instead.
  float* Palog2 = ybuf;   // 4 MB scratch inside ybuf (dead until mm_pass2)

  cvt_f32_bf16<<<16384, 256, 0, stream>>>(W_in, wbf, 16777216);
  alog_part<<<dim3(64, 8), 256, 0, stream>>>(x, W_in, Palog2, xbf);
  alog_reduce<<<512, 256, 0, stream>>>(Palog2, Alog);
  gemm256<<<512, 512, 0, stream>>>(xbf, wbf, zxb, 2048, PROJP, 32);
  mm_pass1<<<dim3(NC - 1, 64), 256, 0, stream>>>(zxb, Alog, Sfin, Dprod);
  scan_combine<<<1024, 256, 0, stream>>>(Sfin, Dprod, Sini);
  mm_pass2<<<dim3(NC, 64), 256, 0, stream>>>(zxb, Alog, Sini, ybuf);
  siluln<<<4096, 256, 0, stream>>>(ybuf, zxb, Dmat, gamma, beta, xbf);
  cvt_f32_bf16<<<4096, 256, 0, stream>>>(W_out, wbf, 4194304);
  gemm_bt<<<512, 256, 0, stream>>>(xbf, wbf, (float*)d_out, 2048, 2048, 16);
}

// Round 15
// 283.836 us; speedup vs baseline: 1.3079x; 1.0120x over previous
//
#include <hip/hip_runtime.h>
#include <stdint.h>
#include <stddef.h>

#define LSEQ   2048
#define DMODEL 2048
#define NH     32
#define DINNER 2048
#define PROJ   8224
#define PROJP  8192   // bf16 GEMM width: x,z,b,c only (a_log handled in fp32)
#define NC     16     // scan chunks
#define CHUNK  128    // LSEQ / NC

typedef __attribute__((ext_vector_type(4))) float f32x4;
typedef __attribute__((ext_vector_type(8))) __bf16 bf16x8;
typedef __attribute__((ext_vector_type(8))) unsigned short u16x8;

__device__ __forceinline__ unsigned short f2bf(float f) {
  union { float f; unsigned u; } uu; uu.f = f;
  unsigned r = uu.u + 0x7FFFu + ((uu.u >> 16) & 1u);
  return (unsigned short)(r >> 16);
}
__device__ __forceinline__ float bf2f(unsigned short u) {
  union { unsigned u; float f; } x; x.u = ((unsigned)u) << 16; return x.f;
}

__device__ __forceinline__ void gl_lds16(const void* g, void* l) {
  __builtin_amdgcn_global_load_lds(
      (__attribute__((address_space(1))) const void*)g,
      (__attribute__((address_space(3))) void*)l, 16, 0, 0);
}

// ---------------- conversions ----------------
__global__ __launch_bounds__(256) void cvt_f32_bf16(
    const float* __restrict__ in, unsigned short* __restrict__ out, int n) {
  int i = (blockIdx.x * 256 + threadIdx.x) * 4;
  if (i + 3 < n) {
    f32x4 v = *(const f32x4*)(in + i);
    ushort4 o;
    o.x = f2bf(v[0]); o.y = f2bf(v[1]); o.z = f2bf(v[2]); o.w = f2bf(v[3]);
    *(ushort4*)(out + i) = o;
  }
}

// ---------------- 256x256 bf16 NT GEMM, BK=64, 4-phase-per-tile (r10-VERIFIED, 140us) ----
__global__ __launch_bounds__(512, 2) void gemm256(
    const unsigned short* __restrict__ A,
    const unsigned short* __restrict__ W,
    unsigned short* __restrict__ C, const int K, const int ldc, const int ntx) {
  __shared__ uint8_t sA[2][32768];
  __shared__ uint8_t sB[2][32768];
  const int tid  = threadIdx.x;
  const int lane = tid & 63;
  const int wid  = tid >> 6;
  const int wm   = wid >> 2;
  const int wnn  = wid & 3;
  const int nwg = gridDim.x;
  const int wg0 = blockIdx.x;
  const int g   = (wg0 & 7) * (nwg >> 3) + (wg0 >> 3);
  const int grp = ntx * 4;
  const int sr  = g / grp, rem = g % grp;
  const int m0  = (sr * 4 + (rem & 3)) * 256;
  const int n0  = (rem >> 2) * 256;

  const int row0 = wid * 8 + (lane >> 3);
  const int ssrc = (lane & 7) ^ (row0 & 7);
  const unsigned short* a_base = A + (size_t)(m0 + row0) * K + ssrc * 8;
  const unsigned short* b_base = W + (size_t)(n0 + row0) * K + ssrc * 8;
  const int wb = wid * 1024;

  f32x4 acc[8][4] = {};
  const int nk = K >> 6;

#pragma unroll
  for (int j = 0; j < 4; ++j) {
    gl_lds16(a_base + (size_t)j * 64 * K, &sA[0][j * 8192 + wb]);
    gl_lds16(b_base + (size_t)j * 64 * K, &sB[0][j * 8192 + wb]);
  }
  asm volatile("s_waitcnt vmcnt(0)" ::: "memory");
  asm volatile("s_barrier" ::: "memory");

  const int ra = wm * 128 + (lane & 15);
  const int rb = wnn * 64 + (lane & 15);
  const int hq = lane >> 4;

  for (int kt = 0; kt < nk; ++kt) {
    const int cur = kt & 1;
    const int nxt = cur ^ 1;
    const unsigned short* an = a_base + (size_t)(kt + 1) * 64;
    const unsigned short* wn_ = b_base + (size_t)(kt + 1) * 64;
    bf16x8 af[8], bv01[2], bv23[2];

    // ---- P0: af@ks0 + bv01@ks0; stage A/B rows 0-127 of tile kt+1 ----
    {
      const int s = hq;
#pragma unroll
      for (int mi = 0; mi < 8; ++mi) {
        const int r = ra + mi * 16;
        af[mi] = *(const bf16x8*)(&sA[cur][r * 128 + ((s ^ (r & 7)) << 4)]);
      }
#pragma unroll
      for (int ni = 0; ni < 2; ++ni) {
        const int r = rb + ni * 16;
        bv01[ni] = *(const bf16x8*)(&sB[cur][r * 128 + ((s ^ (r & 7)) << 4)]);
      }
    }
    if (kt + 1 < nk) {
      gl_lds16(an, &sA[nxt][wb]);
      gl_lds16(an + (size_t)64 * K, &sA[nxt][8192 + wb]);
      gl_lds16(wn_, &sB[nxt][wb]);
      gl_lds16(wn_ + (size_t)64 * K, &sB[nxt][8192 + wb]);
    }
    asm volatile("s_barrier" ::: "memory");
    asm volatile("s_waitcnt lgkmcnt(0)" ::: "memory");
    __builtin_amdgcn_s_setprio(1);
#pragma unroll
    for (int mi = 0; mi < 8; ++mi)
#pragma unroll
      for (int ni = 0; ni < 2; ++ni)
        acc[mi][ni] = __builtin_amdgcn_mfma_f32_16x16x32_bf16(
            af[mi], bv01[ni], acc[mi][ni], 0, 0, 0);
    __builtin_amdgcn_s_setprio(0);
    asm volatile("s_barrier" ::: "memory");

    // ---- P1: bv23@ks0; stage A/B rows 128-255 of tile kt+1 ----
    {
      const int s = hq;
#pragma unroll
      for (int ni = 0; ni < 2; ++ni) {
        const int r = rb + (ni + 2) * 16;
        bv23[ni] = *(const bf16x8*)(&sB[cur][r * 128 + ((s ^ (r & 7)) << 4)]);
      }
    }
    if (kt + 1 < nk) {
      gl_lds16(an + (size_t)128 * K, &sA[nxt][2 * 8192 + wb]);
      gl_lds16(an + (size_t)192 * K, &sA[nxt][3 * 8192 + wb]);
      gl_lds16(wn_ + (size_t)128 * K, &sB[nxt][2 * 8192 + wb]);
      gl_lds16(wn_ + (size_t)192 * K, &sB[nxt][3 * 8192 + wb]);
    }
    asm volatile("s_barrier" ::: "memory");
    asm volatile("s_waitcnt lgkmcnt(0)" ::: "memory");
    __builtin_amdgcn_s_setprio(1);
#pragma unroll
    for (int mi = 0; mi < 8; ++mi)
#pragma unroll
      for (int ni = 0; ni < 2; ++ni)
        acc[mi][ni + 2] = __builtin_amdgcn_mfma_f32_16x16x32_bf16(
            af[mi], bv23[ni], acc[mi][ni + 2], 0, 0, 0);
    __builtin_amdgcn_s_setprio(0);
    asm volatile("s_barrier" ::: "memory");

    // ---- P2: af@ks1 + bv01@ks1 ----
    {
      const int s = 4 + hq;
#pragma unroll
      for (int mi = 0; mi < 8; ++mi) {
        const int r = ra + mi * 16;
        af[mi] = *(const bf16x8*)(&sA[cur][r * 128 + ((s ^ (r & 7)) << 4)]);
      }
#pragma unroll
      for (int ni = 0; ni < 2; ++ni) {
        const int r = rb + ni * 16;
        bv01[ni] = *(const bf16x8*)(&sB[cur][r * 128 + ((s ^ (r & 7)) << 4)]);
      }
    }
    asm volatile("s_barrier" ::: "memory");
    asm volatile("s_waitcnt lgkmcnt(0)" ::: "memory");
    __builtin_amdgcn_s_setprio(1);
#pragma unroll
    for (int mi = 0; mi < 8; ++mi)
#pragma unroll
      for (int ni = 0; ni < 2; ++ni)
        acc[mi][ni] = __builtin_amdgcn_mfma_f32_16x16x32_bf16(
            af[mi], bv01[ni], acc[mi][ni], 0, 0, 0);
    __builtin_amdgcn_s_setprio(0);
    asm volatile("s_barrier" ::: "memory");

    // ---- P3: bv23@ks1 ----
    {
      const int s = 4 + hq;
#pragma unroll
      for (int ni = 0; ni < 2; ++ni) {
        const int r = rb + (ni + 2) * 16;
        bv23[ni] = *(const bf16x8*)(&sB[cur][r * 128 + ((s ^ (r & 7)) << 4)]);
      }
    }
    asm volatile("s_barrier" ::: "memory");
    asm volatile("s_waitcnt lgkmcnt(0)" ::: "memory");
    __builtin_amdgcn_s_setprio(1);
#pragma unroll
    for (int mi = 0; mi < 8; ++mi)
#pragma unroll
      for (int ni = 0; ni < 2; ++ni)
        acc[mi][ni + 2] = __builtin_amdgcn_mfma_f32_16x16x32_bf16(
            af[mi], bv23[ni], acc[mi][ni + 2], 0, 0, 0);
    __builtin_amdgcn_s_setprio(0);
    asm volatile("s_waitcnt vmcnt(0)" ::: "memory");
    asm volatile("s_barrier" ::: "memory");
  }

  const int crow = m0 + wm * 128 + (lane >> 4) * 4;
  const int ccol = n0 + wnn * 64 + (lane & 15);
#pragma unroll
  for (int mi = 0; mi < 8; ++mi)
#pragma unroll
    for (int ni = 0; ni < 4; ++ni) {
      unsigned short* cp = C + (size_t)(crow + mi * 16) * ldc + ccol + ni * 16;
      cp[0] = f2bf(acc[mi][ni][0]);
      cp[(size_t)ldc] = f2bf(acc[mi][ni][1]);
      cp[2 * (size_t)ldc] = f2bf(acc[mi][ni][2]);
      cp[3 * (size_t)ldc] = f2bf(acc[mi][ni][3]);
    }
}

// ---------------- 128x128 bf16 NT GEMM (gemm2), single-barrier loop ----------------
__global__ __launch_bounds__(256) void gemm_bt(
    const unsigned short* __restrict__ A,
    const unsigned short* __restrict__ W,
    float* __restrict__ C, const int K, const int ldc, const int ntx) {
  __shared__ uint8_t sA[2][128 * 64 * 2];
  __shared__ uint8_t sB[2][128 * 64 * 2];
  const int tid  = threadIdx.x;
  const int lane = tid & 63;
  const int wid  = tid >> 6;
  const int wm   = wid >> 1;
  const int wnn  = wid & 1;
  const int nwg = gridDim.x;
  const int wg0 = blockIdx.x;
  const int g   = (wg0 & 7) * (nwg >> 3) + (wg0 >> 3);
  const int grp = ntx * 4;
  const int sr  = g / grp, rem = g % grp;
  const int m0  = (sr * 4 + (rem & 3)) * 128;
  const int n0  = (rem >> 2) * 128;

  const int rowA = tid >> 3;
  const int slot = (tid & 7) ^ (rowA & 7);
  const unsigned short* a_base = A + (size_t)(m0 + rowA) * K + slot * 8;
  const unsigned short* b_base = W + (size_t)(n0 + rowA) * K + slot * 8;
  const int loff = wid * 1024;

  f32x4 acc[4][4] = {};
  const int nk = K >> 6;

#pragma unroll
  for (int j = 0; j < 4; ++j) {
    gl_lds16(a_base + (size_t)j * 32 * K, &sA[0][loff + j * 4096]);
    gl_lds16(b_base + (size_t)j * 32 * K, &sB[0][loff + j * 4096]);
  }

  for (int kt = 0; kt < nk; ++kt) {
    const int cur = kt & 1;
    asm volatile("s_waitcnt vmcnt(0)" ::: "memory");
    asm volatile("s_barrier" ::: "memory");
    if (kt + 1 < nk) {
      const unsigned short* ak = a_base + (kt + 1) * 64;
      const unsigned short* bk = b_base + (kt + 1) * 64;
      const int nb = cur ^ 1;
#pragma unroll
      for (int j = 0; j < 4; ++j) {
        gl_lds16(ak + (size_t)j * 32 * K, &sA[nb][loff + j * 4096]);
        gl_lds16(bk + (size_t)j * 32 * K, &sB[nb][loff + j * 4096]);
      }
    }

    const int ra = wm * 64 + (lane & 15);
    const int rb = wnn * 64 + (lane & 15);
    const int hq = lane >> 4;
#pragma unroll
    for (int ks = 0; ks < 2; ++ks) {
      bf16x8 af[4], bv[4];
      const int s = ks * 4 + hq;
#pragma unroll
      for (int mi = 0; mi < 4; ++mi) {
        const int r = ra + mi * 16;
        af[mi] = *(const bf16x8*)(&sA[cur][r * 128 + ((s ^ (r & 7)) << 4)]);
      }
#pragma unroll
      for (int ni = 0; ni < 4; ++ni) {
        const int r = rb + ni * 16;
        bv[ni] = *(const bf16x8*)(&sB[cur][r * 128 + ((s ^ (r & 7)) << 4)]);
      }
#pragma unroll
      for (int mi = 0; mi < 4; ++mi)
#pragma unroll
        for (int ni = 0; ni < 4; ++ni)
          acc[mi][ni] = __builtin_amdgcn_mfma_f32_16x16x32_bf16(
              af[mi], bv[ni], acc[mi][ni], 0, 0, 0);
    }
  }

  const int crow = m0 + wm * 64 + (lane >> 4) * 4;
  const int ccol = n0 + wnn * 64 + (lane & 15);
#pragma unroll
  for (int mi = 0; mi < 4; ++mi)
#pragma unroll
    for (int ni = 0; ni < 4; ++ni) {
      float* cp = C + (size_t)(crow + mi * 16) * ldc + ccol + ni * 16;
      cp[0] = acc[mi][ni][0];
      cp[(size_t)ldc] = acc[mi][ni][1];
      cp[2 * (size_t)ldc] = acc[mi][ni][2];
      cp[3 * (size_t)ldc] = acc[mi][ni][3];
    }
}

// ---------------- exact fp32 a_log slab + fused x->bf16 emit ----------------
#define AR  64
#define AKT 128
__global__ __launch_bounds__(256) void alog_part(
    const float* __restrict__ x, const float* __restrict__ W_in,
    float* __restrict__ P, unsigned short* __restrict__ xbf) {
  __shared__ float sX[AR][132];
  __shared__ float sW[32][132];
  const int tid = threadIdx.x;
  const int row0 = blockIdx.x * AR;
  const int k0 = blockIdx.y * 256;
  const int r = tid >> 2;
  const int oq = (tid & 3) * 8;
  float acc[8] = {};
#pragma unroll
  for (int kt = 0; kt < 256; kt += AKT) {
    __syncthreads();
    {
      const int lr = tid >> 2;
      const int kk = (tid & 3) * 32;
      const float* src = x + (size_t)(row0 + lr) * DMODEL + k0 + kt + kk;
      float* dst = &sX[lr][kk];
      unsigned short* xb = xbf + (size_t)(row0 + lr) * DMODEL + k0 + kt + kk;
#pragma unroll
      for (int j = 0; j < 32; j += 4) {
        f32x4 v = *(const f32x4*)(src + j);
        *(f32x4*)(dst + j) = v;
        ushort4 o;
        o.x = f2bf(v[0]); o.y = f2bf(v[1]); o.z = f2bf(v[2]); o.w = f2bf(v[3]);
        *(ushort4*)(xb + j) = o;
      }
    }
    {
      const int wr = tid >> 3;
      const int kk = (tid & 7) * 16;
      const float* src = W_in + (size_t)(8192 + wr) * DMODEL + k0 + kt + kk;
      float* dst = &sW[wr][kk];
#pragma unroll
      for (int j = 0; j < 16; j += 4)
        *(f32x4*)(dst + j) = *(const f32x4*)(src + j);
    }
    __syncthreads();
#pragma unroll 2
    for (int k = 0; k < AKT; k += 4) {
      f32x4 xv = *(const f32x4*)&sX[r][k];
#pragma unroll
      for (int o = 0; o < 8; ++o) {
        f32x4 wv = *(const f32x4*)&sW[oq + o][k];
        acc[o] = fmaf(xv[0], wv[0], acc[o]);
        acc[o] = fmaf(xv[1], wv[1], acc[o]);
        acc[o] = fmaf(xv[2], wv[2], acc[o]);
        acc[o] = fmaf(xv[3], wv[3], acc[o]);
      }
    }
  }
  float* dst = P + ((size_t)blockIdx.y * 4096 + row0 + r) * 32 + oq;
  f32x4 v0 = {acc[0], acc[1], acc[2], acc[3]};
  f32x4 v1 = {acc[4], acc[5], acc[6], acc[7]};
  *(f32x4*)dst = v0; *(f32x4*)(dst + 4) = v1;
}

__global__ __launch_bounds__(256) void alog_reduce(
    const float* __restrict__ P, float* __restrict__ Alog) {
  const int idx = blockIdx.x * 256 + threadIdx.x;
  const int row = idx >> 5, o = idx & 31;
  float s = 0.f;
#pragma unroll
  for (int c = 0; c < 8; ++c) s += P[((size_t)c * 4096 + row) * 32 + o];
  Alog[(size_t)row * 32 + o] = s;
}

// ---------------- MFMA chunked scan, pass 1 ----------------
__global__ __launch_bounds__(256) void mm_pass1(
    const unsigned short* __restrict__ zx, const float* __restrict__ Alog,
    float* __restrict__ Sfin, float* __restrict__ Dprod) {
  __shared__ uint8_t sXw[16384];
  __shared__ uint8_t sBT[16384];
  __shared__ float logd[128];
  __shared__ float cums[128];
  const int tid = threadIdx.x;
  const int chunk = blockIdx.x;
  const int bh = blockIdx.y;
  const int h = bh & 31, b = bh >> 5;
  const size_t bL0 = (size_t)b * LSEQ + (size_t)chunk * CHUNK;

  if (tid < 128) logd[tid] = -__expf(Alog[(bL0 + tid) * 32 + h]);
  __syncthreads();
  if (tid < 128) {
    float s = 0.f;
#pragma unroll 4
    for (int r = 0; r <= tid; ++r) s += logd[r];
    cums[tid] = s;
  }
  __syncthreads();
  const float clast = cums[127];

  {
    const int u = tid & 127, ph = (tid >> 7) * 32;
    const int half = u >> 6, uk = u & 63;
    const float wfac = __expf(clast - cums[u]);
    const unsigned short* xrow = zx + (bL0 + u) * (size_t)PROJP + h * 64 + ph;
#pragma unroll
    for (int j = 0; j < 4; ++j) {
      u16x8 xv = *(const u16x8*)(xrow + j * 8);
      u16x8 bv = *(const u16x8*)(xrow + 4096 + j * 8);
#pragma unroll
      for (int e = 0; e < 8; ++e) {
        const int p = ph + j * 8 + e;
        const int byteoff = half * 8192 + p * 128 +
                            (((uk >> 3) ^ (p & 7)) << 4) + (uk & 7) * 2;
        *(unsigned short*)(sXw + byteoff) = f2bf(bf2f(xv[e]) * wfac);
        *(unsigned short*)(sBT + byteoff) = bv[e];
      }
    }
  }
  __syncthreads();

  const int lane = tid & 63, w = tid >> 6;
  const int ra = w * 16 + (lane & 15);
  const int s0 = lane >> 4;
  f32x4 acc[4] = {};
#pragma unroll
  for (int half = 0; half < 2; ++half)
#pragma unroll
    for (int ks = 0; ks < 2; ++ks) {
      const int s = ks * 4 + s0;
      bf16x8 af = *(const bf16x8*)(sXw + half * 8192 + ra * 128 + ((s ^ (ra & 7)) << 4));
#pragma unroll
      for (int ni = 0; ni < 4; ++ni) {
        const int rb = ni * 16 + (lane & 15);
        bf16x8 bf = *(const bf16x8*)(sBT + half * 8192 + rb * 128 + ((s ^ (rb & 7)) << 4));
        acc[ni] = __builtin_amdgcn_mfma_f32_16x16x32_bf16(af, bf, acc[ni], 0, 0, 0);
      }
    }

  float* sf = Sfin + ((size_t)bh * NC + chunk) * 4096;
  const int prow = w * 16 + (lane >> 4) * 4;
  const int ncol = lane & 15;
#pragma unroll
  for (int ni = 0; ni < 4; ++ni)
#pragma unroll
    for (int reg = 0; reg < 4; ++reg)
      sf[(size_t)(prow + reg) * 64 + ni * 16 + ncol] = acc[ni][reg];
  if (tid == 0) Dprod[bh * NC + chunk] = __expf(clast);
}

// Combine: exclusive prefix over chunks -> per-chunk initial states.
__global__ __launch_bounds__(256) void scan_combine(
    const float* __restrict__ Sfin, const float* __restrict__ Dp,
    float* __restrict__ Sini) {
  const int idx = blockIdx.x * 256 + threadIdx.x;
  const int bh = idx >> 12;
  const int e = idx & 4095;
  const float* sf = Sfin + (size_t)bh * NC * 4096 + e;
  float* si = Sini + (size_t)bh * NC * 4096 + e;
  float S = 0.f;
#pragma unroll
  for (int c = 0; c < NC; ++c) {
    si[(size_t)c * 4096] = S;
    if (c < NC - 1) S = fmaf(S, Dp[bh * NC + c], sf[(size_t)c * 4096]);
  }
}

// ---------------- MFMA chunked scan, pass 2 (y emitted as bf16) ----------------
__global__ __launch_bounds__(256) void mm_pass2(
    const unsigned short* __restrict__ zx, const float* __restrict__ Alog,
    const float* __restrict__ Sini, unsigned short* __restrict__ y) {
  __shared__ uint8_t smem[65536];
  __shared__ float logd[128];
  __shared__ float cums[128];
  const int tid = threadIdx.x;
  const int chunk = blockIdx.x;
  const int bh = blockIdx.y;
  const int h = bh & 31, b = bh >> 5;
  const size_t bL0 = (size_t)b * LSEQ + (size_t)chunk * CHUNK;
  const int lane = tid & 63, w = tid >> 6;

  if (tid < 128) logd[tid] = -__expf(Alog[(bL0 + tid) * 32 + h]);
  {
    const int rowS = tid >> 3;
    const int slot = (tid & 7) ^ (rowS & 7);
    const unsigned short* cb = zx + (bL0 + rowS) * (size_t)PROJP + 6144 + h * 64 + slot * 8;
    const unsigned short* bb = zx + (bL0 + rowS) * (size_t)PROJP + 4096 + h * 64 + slot * 8;
    const int dbase = w * 1024;
#pragma unroll
    for (int j = 0; j < 4; ++j) {
      gl_lds16(cb + (size_t)j * 32 * PROJP, smem + dbase + j * 4096);
      gl_lds16(bb + (size_t)j * 32 * PROJP, smem + 16384 + dbase + j * 4096);
    }
  }
  __syncthreads();
  if (tid < 128) {
    float s = 0.f;
#pragma unroll 4
    for (int r = 0; r <= tid; ++r) s += logd[r];
    cums[tid] = s;
  }
  {
    const int u = tid & 127, ph = (tid >> 7) * 32;
    const int half = u >> 6, uk = u & 63;
    const unsigned short* xrow = zx + (bL0 + u) * (size_t)PROJP + h * 64 + ph;
#pragma unroll
    for (int j = 0; j < 4; ++j) {
      u16x8 xv = *(const u16x8*)(xrow + j * 8);
#pragma unroll
      for (int e = 0; e < 8; ++e) {
        const int p = ph + j * 8 + e;
        *(unsigned short*)(smem + 32768 + half * 8192 + p * 128 +
                           (((uk >> 3) ^ (p & 7)) << 4) + (uk & 7) * 2) = xv[e];
      }
    }
  }
  {
    const float* si = Sini + ((size_t)bh * NC + chunk) * 4096 + tid * 16;
    const int p = tid >> 2;
#pragma unroll
    for (int gq = 0; gq < 2; ++gq) {
      u16x8 hv, lv;
#pragma unroll
      for (int e = 0; e < 8; ++e) {
        float v = si[gq * 8 + e];
        unsigned short hu = f2bf(v);
        hv[e] = hu;
        lv[e] = f2bf(v - bf2f(hu));
      }
      const int slotg = (tid & 3) * 2 + gq;
      const int byte_ = p * 128 + ((slotg ^ (p & 7)) << 4);
      *(u16x8*)(smem + 49152 + byte_) = hv;
      *(u16x8*)(smem + 57344 + byte_) = lv;
    }
  }
  __syncthreads();

  const int rl = lane & 15, s0 = lane >> 4;
  const int tb = w * 32;
  f32x4 accG[2][8] = {};
  f32x4 acc2[2][4] = {};
#pragma unroll
  for (int ks = 0; ks < 2; ++ks) {
    const int s = ks * 4 + s0;
    bf16x8 ca[2];
#pragma unroll
    for (int mi = 0; mi < 2; ++mi) {
      const int r = tb + mi * 16 + rl;
      ca[mi] = *(const bf16x8*)(smem + r * 128 + ((s ^ (r & 7)) << 4));
    }
#pragma unroll
    for (int ni = 0; ni < 8; ++ni) {
      const int r = ni * 16 + rl;
      bf16x8 bf = *(const bf16x8*)(smem + 16384 + r * 128 + ((s ^ (r & 7)) << 4));
#pragma unroll
      for (int mi = 0; mi < 2; ++mi)
        accG[mi][ni] = __builtin_amdgcn_mfma_f32_16x16x32_bf16(ca[mi], bf, accG[mi][ni], 0, 0, 0);
    }
#pragma unroll
    for (int ni = 0; ni < 4; ++ni) {
      const int r = ni * 16 + rl;
      bf16x8 sh = *(const bf16x8*)(smem + 49152 + r * 128 + ((s ^ (r & 7)) << 4));
      bf16x8 sl = *(const bf16x8*)(smem + 57344 + r * 128 + ((s ^ (r & 7)) << 4));
#pragma unroll
      for (int mi = 0; mi < 2; ++mi) {
        acc2[mi][ni] = __builtin_amdgcn_mfma_f32_16x16x32_bf16(ca[mi], sh, acc2[mi][ni], 0, 0, 0);
        acc2[mi][ni] = __builtin_amdgcn_mfma_f32_16x16x32_bf16(ca[mi], sl, acc2[mi][ni], 0, 0, 0);
      }
    }
  }
  __syncthreads();

  float ct[2][4];
#pragma unroll
  for (int mi = 0; mi < 2; ++mi)
#pragma unroll
    for (int reg = 0; reg < 4; ++reg)
      ct[mi][reg] = cums[tb + mi * 16 + (lane >> 4) * 4 + reg];
#pragma unroll
  for (int ni = 0; ni < 8; ++ni) {
    const int u = ni * 16 + rl;
    const float cu = cums[u];
    const int Ph = u >> 6, uk = u & 63;
#pragma unroll
    for (int mi = 0; mi < 2; ++mi)
#pragma unroll
      for (int reg = 0; reg < 4; ++reg) {
        const int t = tb + mi * 16 + (lane >> 4) * 4 + reg;
        float v = (u <= t) ? accG[mi][ni][reg] * __expf(ct[mi][reg] - cu) : 0.f;
        *(unsigned short*)(smem + Ph * 16384 + t * 128 +
                           (((uk >> 3) ^ (t & 7)) << 4) + (uk & 7) * 2) = f2bf(v);
      }
  }
  __syncthreads();

  f32x4 accY[2][4] = {};
#pragma unroll
  for (int half = 0; half < 2; ++half)
#pragma unroll
    for (int ks = 0; ks < 2; ++ks) {
      const int s = ks * 4 + s0;
      bf16x8 pa[2];
#pragma unroll
      for (int mi = 0; mi < 2; ++mi) {
        const int r = tb + mi * 16 + rl;
        pa[mi] = *(const bf16x8*)(smem + half * 16384 + r * 128 + ((s ^ (r & 7)) << 4));
      }
#pragma unroll
      for (int ni = 0; ni < 4; ++ni) {
        const int r = ni * 16 + rl;
        bf16x8 xb = *(const bf16x8*)(smem + 32768 + half * 8192 + r * 128 + ((s ^ (r & 7)) << 4));
#pragma unroll
        for (int mi = 0; mi < 2; ++mi)
          accY[mi][ni] = __builtin_amdgcn_mfma_f32_16x16x32_bf16(pa[mi], xb, accY[mi][ni], 0, 0, 0);
      }
    }

#pragma unroll
  for (int mi = 0; mi < 2; ++mi)
#pragma unroll
    for (int reg = 0; reg < 4; ++reg) {
      const int t = tb + mi * 16 + (lane >> 4) * 4 + reg;
      const float wt = __expf(ct[mi][reg]);
#pragma unroll
      for (int ni = 0; ni < 4; ++ni) {
        const int p = ni * 16 + rl;
        y[(bL0 + t) * (size_t)DINNER + h * 64 + p] =
            f2bf(accY[mi][ni][reg] + wt * acc2[mi][ni][reg]);
      }
    }
}

// ---------------- fused (y + D*x)*silu(z) + LayerNorm -> bf16 (y in bf16) ----------
__global__ __launch_bounds__(256) void siluln(
    const unsigned short* __restrict__ yin, const unsigned short* __restrict__ zx,
    const float* __restrict__ Dmat,
    const float* __restrict__ gamma, const float* __restrict__ beta,
    unsigned short* __restrict__ out) {
  const int row = blockIdx.x;
  const int tid = threadIdx.x;
  const int lane = tid & 63;
  const int wid = tid >> 6;
  const int col = tid * 8;
  const unsigned short* yp = yin + (size_t)row * DINNER + col;
  const unsigned short* zp = zx + (size_t)row * PROJP + DINNER + col;
  const unsigned short* xp = zx + (size_t)row * PROJP + col;
  u16x8 yv = *(const u16x8*)yp;
  u16x8 zv = *(const u16x8*)zp;
  u16x8 xv = *(const u16x8*)xp;
  f32x4 d0 = *(const f32x4*)(Dmat + col), d1 = *(const f32x4*)(Dmat + col + 4);
  float v[8];
#pragma unroll
  for (int i = 0; i < 8; ++i) {
    float z = bf2f(zv[i]);
    float dd = (i < 4) ? d0[i] : d1[i - 4];
    float yy = bf2f(yv[i]) + bf2f(xv[i]) * dd;
    v[i] = yy * (z / (1.f + __expf(-z)));
  }
  float t1 = 0.f, t2 = 0.f;
#pragma unroll
  for (int i = 0; i < 8; ++i) { t1 += v[i]; t2 += v[i] * v[i]; }
#pragma unroll
  for (int off = 1; off < 64; off <<= 1) {
    t1 += __shfl_xor(t1, off);
    t2 += __shfl_xor(t2, off);
  }
  __shared__ float red[8];
  if (lane == 0) { red[wid] = t1; red[wid + 4] = t2; }
  __syncthreads();
  float ts1 = red[0] + red[1] + red[2] + red[3];
  float ts2 = red[4] + red[5] + red[6] + red[7];
  float mu = ts1 * (1.f / 2048.f);
  float var = ts2 * (1.f / 2048.f) - mu * mu;
  float rs = rsqrtf(var + 1e-5f);
  f32x4 g0 = *(const f32x4*)(gamma + col), g1 = *(const f32x4*)(gamma + col + 4);
  f32x4 b0 = *(const f32x4*)(beta + col),  b1 = *(const f32x4*)(beta + col + 4);
  u16x8 ov;
#pragma unroll
  for (int i = 0; i < 4; ++i)
    ov[i] = f2bf((v[i] - mu) * rs * g0[i] + b0[i]);
#pragma unroll
  for (int i = 0; i < 4; ++i)
    ov[i + 4] = f2bf((v[i + 4] - mu) * rs * g1[i] + b1[i]);
  *(u16x8*)(out + (size_t)row * DINNER + col) = ov;
}

// ---------------- launch ----------------
extern "C" void kernel_launch(void* const* d_in, const int* in_sizes, int n_in,
                              void* d_out, int out_size, void* d_ws, size_t ws_size,
                              hipStream_t stream) {
  (void)in_sizes; (void)n_in; (void)out_size; (void)ws_size;
  const float* x     = (const float*)d_in[0];
  const float* W_in  = (const float*)d_in[1];
  const float* W_out = (const float*)d_in[2];
  const float* gamma = (const float*)d_in[3];
  const float* beta  = (const float*)d_in[4];
  const float* Dmat  = (const float*)d_in[5];

  uint8_t* ws = (uint8_t*)d_ws;
  unsigned short* xbf = (unsigned short*)ws;                 // 16 MB; later y_ln
  unsigned short* wbf = (unsigned short*)(ws + 16777216);    // 34 MB region (W)
  float* Sfin  = (float*)(ws + 16777216);                    // reused after gemm1? (dead wbf region ONLY after gemm256) -- Sfin used after gemm256: OK
  float* Sini  = (float*)(ws + 33554432);
  float* Dprod = (float*)(ws + 50331648);
  float* Alog  = (float*)(ws + 50855936);                    // 512 KB
  unsigned short* zxb = (unsigned short*)(ws + 51380224);    // 64 MB (bf16, stride 8192)
  unsigned short* ybuf = (unsigned short*)(ws + 119537664);  // 16.8 MB (bf16 y)
  float* Palog2 = (float*)(ws + 119537664);                  // 4 MB scratch (dead until mm_pass2)

  cvt_f32_bf16<<<16384, 256, 0, stream>>>(W_in, wbf, 16777216);
  alog_part<<<dim3(64, 8), 256, 0, stream>>>(x, W_in, Palog2, xbf);
  alog_reduce<<<512, 256, 0, stream>>>(Palog2, Alog);
  gemm256<<<512, 512, 0, stream>>>(xbf, wbf, zxb, 2048, PROJP, 32);
  mm_pass1<<<dim3(NC - 1, 64), 256, 0, stream>>>(zxb, Alog, Sfin, Dprod);
  scan_combine<<<1024, 256, 0, stream>>>(Sfin, Dprod, Sini);
  mm_pass2<<<dim3(NC, 64), 256, 0, stream>>>(zxb, Alog, Sini, ybuf);
  siluln<<<4096, 256, 0, stream>>>(ybuf, zxb, Dmat, gamma, beta, xbf);
  cvt_f32_bf16<<<4096, 256, 0, stream>>>(W_out, wbf, 4194304);
  gemm_bt<<<512, 256, 0, stream>>>(xbf, wbf, (float*)d_out, 2048, 2048, 16);
}